// Round 5
// baseline (1212.999 us; speedup 1.0000x reference)
//
#include <hip/hip_runtime.h>
#include <math.h>

#define E 1152
#define H 16
#define HD 72
#define B 32
#define S 4096
#define IDIM 4304
#define NSL 16            // slices per batch image
#define ROWS 256          // rows per block
#define STG 32            // stages of 8 rows

#define NEGF (-3.402823466e38f)
#define SCALE 0.1178511301977579f  // 1/sqrt(72)

#define GLOAD_LDS16(gp, lp) __builtin_amdgcn_global_load_lds( \
    (const __attribute__((address_space(1))) unsigned int*)(gp), \
    (__attribute__((address_space(3))) unsigned int*)(lp), 16, 0, 0)

__device__ __forceinline__ float wredsum(float v){
  v += __shfl_xor(v,32); v += __shfl_xor(v,16); v += __shfl_xor(v,8);
  v += __shfl_xor(v,4);  v += __shfl_xor(v,2);  v += __shfl_xor(v,1);
  return v;
}

// q[j] = probe . wq[j,:] + bq[j]
__global__ void k_q(const float* __restrict__ probe, const float* __restrict__ ipw,
                    const float* __restrict__ ipb, float* __restrict__ q){
  int tid = threadIdx.x, lane = tid & 63, w = tid >> 6;
  int j = blockIdx.x*4 + w;
  const float* wr = ipw + (size_t)j*E;
  float s = 0.f;
  #pragma unroll
  for (int t=0;t<18;++t){ int e = lane + 64*t; s = fmaf(probe[e], wr[e], s); }
  s = wredsum(s);
  if (lane==0) q[j] = s + ipb[j];
}

// qk[h*E+e] = sum_d q[h*72+d]*wk[h*72+d, e]; cb[h] = q[h]·bk_h
__global__ void k_qk(const float* __restrict__ q, const float* __restrict__ ipw,
                     const float* __restrict__ ipb, float* __restrict__ qk,
                     float* __restrict__ cb){
  int idx = blockIdx.x*256 + threadIdx.x;   // < H*E
  int h = idx / E, e = idx % E;
  float s = 0.f;
  #pragma unroll 8
  for (int d=0; d<HD; ++d)
    s = fmaf(q[h*HD+d], ipw[(size_t)(E + h*HD + d)*E + e], s);
  qk[idx] = s;
  if (idx < H){
    float c = 0.f;
    for (int d=0; d<HD; ++d) c = fmaf(q[idx*HD+d], ipb[E + idx*HD + d], c);
    cb[idx] = c;
  }
}

// ---------------- fused single pass over hidden (flash-style):
// grid: 32 b x 16 slices (256 rows); block = 4 waves; wave owns heads 4w..4w+3.
// Double-buffered LDS staging, one barrier per stage, deferred-max per stage.
__global__ __launch_bounds__(256) void k_fused(
    const float* __restrict__ hidden, const float* __restrict__ qk,
    const float* __restrict__ cb, const int* __restrict__ mask,
    float* __restrict__ part, float* __restrict__ part_ml){
  __shared__ float tile[2][8*E];   // 2 x 36864 B
  int tid = threadIdx.x, lane = tid & 63, w = tid >> 6;
  int b = blockIdx.x >> 4, sl = blockIdx.x & 15;
  int s0 = sl*ROWS;
  int lb = lane & 0x3C;

  float2 qkr[4][9];
  #pragma unroll
  for (int j=0;j<4;++j){
    const float2* qp = (const float2*)(qk + (size_t)(4*w+j)*E);
    #pragma unroll
    for (int k=0;k<9;++k) qkr[j][k] = qp[lane + 64*k];
  }
  float cbv = cb[4*w + (lane & 3)];
  bool o1 = (lane & 1), o2 = (lane & 2);

  float m = -INFINITY, l = 0.f;
  float2 acc[4][9];
  #pragma unroll
  for (int j=0;j<4;++j)
    #pragma unroll
    for (int k=0;k<9;++k){ acc[j][k].x = 0.f; acc[j][k].y = 0.f; }

  const float* base = hidden + ((size_t)b*S + s0)*E;
  // prologue: stage 0 -> tile[0]
  #pragma unroll
  for (int i=0;i<9;++i){
    int c = i*4 + w;
    GLOAD_LDS16(base + c*256 + lane*4, &tile[0][c*256]);
  }

  for (int st=0; st<STG; ++st){
    __syncthreads();              // compiler drains vmcnt before barrier
    int p = st & 1;
    if (st+1 < STG){
      const float* src = base + (size_t)(st+1)*8*E;
      #pragma unroll
      for (int i=0;i<9;++i){
        int c = i*4 + w;
        GLOAD_LDS16(src + c*256 + lane*4, &tile[p^1][c*256]);
      }
    }
    const float* tp = tile[p];

    // per-stage mask: lanes 0..7 hold rows 0..7
    int mv = mask[(size_t)b*S + s0 + st*8 + (lane & 7)];
    float am = (1.0f - (float)mv) * NEGF;

    // ---- pass A: scores for 8 rows (hv streamed, 1 live float2)
    float v[8];
    #pragma unroll
    for (int r=0;r<8;++r){
      const float2* row = (const float2*)(tp + r*E);
      float a0=0.f, a1=0.f, a2=0.f, a3=0.f;
      #pragma unroll
      for (int k=0;k<9;++k){
        float2 hv = row[lane + 64*k];
        a0 = fmaf(hv.x, qkr[0][k].x, fmaf(hv.y, qkr[0][k].y, a0));
        a1 = fmaf(hv.x, qkr[1][k].x, fmaf(hv.y, qkr[1][k].y, a1));
        a2 = fmaf(hv.x, qkr[2][k].x, fmaf(hv.y, qkr[2][k].y, a2));
        a3 = fmaf(hv.x, qkr[3][k].x, fmaf(hv.y, qkr[3][k].y, a3));
      }
      // packed butterfly: every lane ends with head (4w + (lane&3)) sum
      float c01 = o1 ? a1 : a0, d01 = o1 ? a0 : a1;
      c01 += __shfl_xor(d01, 1);
      float c23 = o1 ? a3 : a2, d23 = o1 ? a2 : a3;
      c23 += __shfl_xor(d23, 1);
      float vv = o2 ? c23 : c01, dv = o2 ? c01 : c23;
      vv += __shfl_xor(dv, 2);
      vv += __shfl_xor(vv,4); vv += __shfl_xor(vv,8);
      vv += __shfl_xor(vv,16); vv += __shfl_xor(vv,32);
      v[r] = SCALE*(vv + cbv) + __shfl(am, r);
    }

    // ---- deferred-max rescale, once per stage (uniform branch)
    float smax = v[0];
    #pragma unroll
    for (int r=1;r<8;++r) smax = fmaxf(smax, v[r]);
    if (__any(smax > m + 8.0f)){
      float mn = fmaxf(m, smax);
      float f  = __expf(m - mn);
      m = mn; l *= f;
      float f0 = __shfl(f, lb|0), f1 = __shfl(f, lb|1);
      float f2 = __shfl(f, lb|2), f3 = __shfl(f, lb|3);
      #pragma unroll
      for (int k=0;k<9;++k){
        acc[0][k].x *= f0; acc[0][k].y *= f0;
        acc[1][k].x *= f1; acc[1][k].y *= f1;
        acc[2][k].x *= f2; acc[2][k].y *= f2;
        acc[3][k].x *= f3; acc[3][k].y *= f3;
      }
    }
    #pragma unroll
    for (int r=0;r<8;++r){ v[r] = __expf(v[r] - m); l += v[r]; }

    // ---- pass B: weighted accumulate (hv re-read, streamed)
    #pragma unroll
    for (int r=0;r<8;++r){
      float w0 = __shfl(v[r], lb|0), w1 = __shfl(v[r], lb|1);
      float w2 = __shfl(v[r], lb|2), w3 = __shfl(v[r], lb|3);
      const float2* row = (const float2*)(tp + r*E);
      #pragma unroll
      for (int k=0;k<9;++k){
        float2 hv = row[lane + 64*k];
        acc[0][k].x = fmaf(w0, hv.x, acc[0][k].x); acc[0][k].y = fmaf(w0, hv.y, acc[0][k].y);
        acc[1][k].x = fmaf(w1, hv.x, acc[1][k].x); acc[1][k].y = fmaf(w1, hv.y, acc[1][k].y);
        acc[2][k].x = fmaf(w2, hv.x, acc[2][k].x); acc[2][k].y = fmaf(w2, hv.y, acc[2][k].y);
        acc[3][k].x = fmaf(w3, hv.x, acc[3][k].x); acc[3][k].y = fmaf(w3, hv.y, acc[3][k].y);
      }
    }
  }

  if (lane < 4){
    size_t o = ((size_t)(b*NSL + sl)*16 + 4*w + lane)*2;
    part_ml[o] = m; part_ml[o+1] = l;
  }
  #pragma unroll
  for (int j=0;j<4;++j){
    float2* dst = (float2*)(part + ((size_t)(b*NSL + sl)*H + 4*w + j)*E);
    #pragma unroll
    for (int k=0;k<9;++k) dst[lane + 64*k] = acc[j][k];
  }
}

// combine slice-partials -> per-slice final scale = exp(m_sl - M)/L_total
__global__ void k_mlcomb(const float* __restrict__ part_ml, float* __restrict__ scale){
  int t = threadIdx.x;            // 512 = 32*16
  int b = t >> 4, h = t & 15;
  float M = -INFINITY, L = 0.f;
  for (int c = 0; c < NSL; ++c){
    size_t o = ((size_t)(b*NSL + c)*16 + h)*2;
    float om = part_ml[o], ol = part_ml[o+1];
    float nm = fmaxf(M, om);
    L = L*__expf(M - nm) + ol*__expf(om - nm);
    M = nm;
  }
  float invL = 1.0f / L;
  for (int c = 0; c < NSL; ++c){
    size_t o = ((size_t)(b*NSL + c)*16 + h)*2;
    scale[(size_t)(b*NSL + c)*16 + h] = __expf(part_ml[o] - M) * invL;
  }
}

// ctx[b][h][e] = sum_sl part[b][sl][h][e] * scale[b][sl][h]
__global__ void k_ctxred(const float* __restrict__ part, const float* __restrict__ scale,
                         float* __restrict__ ctx){
  int idx = blockIdx.x*256 + threadIdx.x;  // < B*H*E
  int b = idx / (H*E); int he = idx % (H*E); int h = he / E;
  float s = 0.f;
  #pragma unroll 4
  for (int sl=0; sl<NSL; ++sl)
    s = fmaf(part[(size_t)(b*NSL+sl)*H*E + he], scale[(size_t)(b*NSL+sl)*16 + h], s);
  ctx[idx] = s;
}

// pooled[b, j] = wv[j,:]·ctx[b, j/72, :] + bv[j]
__global__ void k_pool(const float* __restrict__ ctx, const float* __restrict__ ipw,
                       const float* __restrict__ ipb, float* __restrict__ pooled){
  int tid = threadIdx.x, lane = tid & 63, w = tid >> 6;
  int j = blockIdx.x*4 + w;
  int h = j / HD;
  const float* wr = ipw + (size_t)2*E*E + (size_t)j*E;
  float acc[32];
  #pragma unroll
  for (int b_=0;b_<32;++b_) acc[b_]=0.f;
  #pragma unroll
  for (int t=0;t<18;++t){
    int e = lane + 64*t;
    float wv = wr[e];
    #pragma unroll
    for (int b_=0;b_<32;++b_)
      acc[b_] = fmaf(wv, ctx[(size_t)(b_*H + h)*E + e], acc[b_]);
  }
  #pragma unroll
  for (int b_=0;b_<32;++b_){
    float s = wredsum(acc[b_]);
    if (lane==b_) pooled[(size_t)b_*E + j] = s + ipb[2*E + j];
  }
}

__global__ void k_outproj(const float* __restrict__ pooled, const float* __restrict__ ow,
                          const float* __restrict__ ob, float* __restrict__ resid){
  int tid = threadIdx.x, lane = tid & 63, w = tid >> 6;
  int i = blockIdx.x*4 + w;
  const float* wr = ow + (size_t)i*E;
  float acc[32];
  #pragma unroll
  for (int b_=0;b_<32;++b_) acc[b_]=0.f;
  #pragma unroll
  for (int t=0;t<18;++t){
    int e = lane + 64*t;
    float wv = wr[e];
    #pragma unroll
    for (int b_=0;b_<32;++b_)
      acc[b_] = fmaf(wv, pooled[(size_t)b_*E + e], acc[b_]);
  }
  #pragma unroll
  for (int b_=0;b_<32;++b_){
    float s = wredsum(acc[b_]);
    if (lane==b_) resid[(size_t)b_*E + i] = s + ob[i];
  }
}

__global__ void k_ln(const float* __restrict__ resid, const float* __restrict__ g,
                     const float* __restrict__ be, float* __restrict__ x){
  __shared__ float red[8];
  int b = blockIdx.x, tid = threadIdx.x, lane = tid & 63, w = tid >> 6;
  const float* r = resid + (size_t)b*E;
  float s = 0.f, s2 = 0.f;
  for (int e=tid; e<E; e+=256){ float v = r[e]; s += v; s2 = fmaf(v,v,s2); }
  s = wredsum(s); s2 = wredsum(s2);
  if (lane==0){ red[w]=s; red[4+w]=s2; }
  __syncthreads();
  float S1 = red[0]+red[1]+red[2]+red[3];
  float S2 = red[4]+red[5]+red[6]+red[7];
  float mu  = S1*(1.0f/E);
  float var = S2*(1.0f/E) - mu*mu;
  float inv = rsqrtf(var + 1e-6f);
  for (int e=tid; e<E; e+=256){
    float v = (r[e]-mu)*inv;
    x[(size_t)b*E + e] = v*g[e] + be[e];
  }
}

__device__ __forceinline__ float gelu_tanh(float u){
  float u3 = u*u*u;
  float t = tanhf(0.7978845608028654f*(u + 0.044715f*u3));
  return 0.5f*u*(1.0f+t);
}

__global__ __launch_bounds__(256) void k_fc1(
    const float* __restrict__ x, const float* __restrict__ w1,
    const float* __restrict__ b1, float* __restrict__ h1){
  int tid = threadIdx.x, lane = tid & 63, w = tid >> 6;
  int wid = blockIdx.x*4 + w;      // < 2152
  int i0 = wid*2;
  float acc[2][32];
  #pragma unroll
  for (int ii=0;ii<2;++ii)
    #pragma unroll
    for (int b_=0;b_<32;++b_) acc[ii][b_]=0.f;
  #pragma unroll
  for (int t=0;t<18;++t){
    int e = lane + 64*t;
    float f0 = w1[(size_t)i0*E + e];
    float f1 = w1[(size_t)(i0+1)*E + e];
    #pragma unroll
    for (int b_=0;b_<32;++b_){
      float xv = x[(size_t)b_*E + e];
      acc[0][b_] = fmaf(f0, xv, acc[0][b_]);
      acc[1][b_] = fmaf(f1, xv, acc[1][b_]);
    }
  }
  #pragma unroll
  for (int ii=0;ii<2;++ii)
    #pragma unroll
    for (int b_=0;b_<32;++b_){
      float s = wredsum(acc[ii][b_]);
      if (lane==b_) h1[(size_t)b_*IDIM + i0 + ii] = gelu_tanh(s + b1[i0+ii]);
    }
}

__global__ __launch_bounds__(256) void k_fc2(
    const float* __restrict__ h1, const float* __restrict__ w2,
    const float* __restrict__ b2, const float* __restrict__ resid,
    float* __restrict__ out){
  int tid = threadIdx.x, lane = tid & 63, w = tid >> 6;
  int wid = blockIdx.x*4 + w;      // < 576
  int i0 = wid*2;
  float acc[2][32];
  #pragma unroll
  for (int ii=0;ii<2;++ii)
    #pragma unroll
    for (int b_=0;b_<32;++b_) acc[ii][b_]=0.f;
  #pragma unroll 2
  for (int t=0;t<68;++t){
    int e = lane + 64*t;
    if (e < IDIM){
      float f0 = w2[(size_t)i0*IDIM + e];
      float f1 = w2[(size_t)(i0+1)*IDIM + e];
      #pragma unroll
      for (int b_=0;b_<32;++b_){
        float hvv = h1[(size_t)b_*IDIM + e];
        acc[0][b_] = fmaf(f0, hvv, acc[0][b_]);
        acc[1][b_] = fmaf(f1, hvv, acc[1][b_]);
      }
    }
  }
  #pragma unroll
  for (int ii=0;ii<2;++ii)
    #pragma unroll
    for (int b_=0;b_<32;++b_){
      float s = wredsum(acc[ii][b_]);
      if (lane==b_){
        int i = i0 + ii;
        out[(size_t)b_*E + i] = resid[(size_t)b_*E + i] + s + b2[i];
      }
    }
}

extern "C" void kernel_launch(void* const* d_in, const int* in_sizes, int n_in,
                              void* d_out, int out_size, void* d_ws, size_t ws_size,
                              hipStream_t stream){
  const float* hidden = (const float*)d_in[0];
  const int*   mask   = (const int*)d_in[1];
  const float* probe  = (const float*)d_in[2];
  const float* ipw    = (const float*)d_in[3];
  const float* ipb    = (const float*)d_in[4];
  const float* ow     = (const float*)d_in[5];
  const float* ob     = (const float*)d_in[6];
  const float* ln_g   = (const float*)d_in[7];
  const float* ln_b   = (const float*)d_in[8];
  const float* w1     = (const float*)d_in[9];
  const float* b1     = (const float*)d_in[10];
  const float* w2     = (const float*)d_in[11];
  const float* b2     = (const float*)d_in[12];
  float* out = (float*)d_out;
  float* ws  = (float*)d_ws;

  size_t off = 0;
  float* q  = ws + off; off += E;
  float* qk = ws + off; off += H*E;
  float* cb = ws + off; off += 16;
  float* part_ml = ws + off; off += 32*NSL*16*2;
  float* scale   = ws + off; off += 32*NSL*16;
  float* part    = ws + off; off += (size_t)B*NSL*H*E;  // 37.7 MB
  float* ctx     = ws + off; off += (size_t)B*H*E;
  float* pooled  = ws + off; off += (size_t)B*E;
  float* resid   = ws + off; off += (size_t)B*E;
  float* x       = ws + off; off += (size_t)B*E;
  float* h1      = ws + off;

  k_q       <<<288, 256, 0, stream>>>(probe, ipw, ipb, q);
  k_qk      <<<72, 256, 0, stream>>>(q, ipw, ipb, qk, cb);
  k_fused   <<<B*NSL, 256, 0, stream>>>(hidden, qk, cb, mask, part, part_ml);
  k_mlcomb  <<<1, 512, 0, stream>>>(part_ml, scale);
  k_ctxred  <<<2304, 256, 0, stream>>>(part, scale, ctx);
  k_pool    <<<288, 256, 0, stream>>>(ctx, ipw, ipb, pooled);
  k_outproj <<<288, 256, 0, stream>>>(pooled, ow, ob, resid);
  k_ln      <<<32, 256, 0, stream>>>(resid, ln_g, ln_b, x);
  k_fc1     <<<538, 256, 0, stream>>>(x, w1, b1, h1);
  k_fc2     <<<144, 256, 0, stream>>>(h1, w2, b2, resid, out);
}

// Round 6
// 1090.246 us; speedup vs baseline: 1.1126x; 1.1126x over previous
//
#include <hip/hip_runtime.h>
#include <math.h>

#define E 1152
#define H 16
#define HD 72
#define B 32
#define S 4096
#define IDIM 4304
#define NSL 16

#define NEGF (-3.402823466e38f)
#define SCALE 0.1178511301977579f  // 1/sqrt(72)

typedef short short8 __attribute__((ext_vector_type(8)));
typedef float f32x4 __attribute__((ext_vector_type(4)));

#define GLOAD_LDS16(gp, lp) __builtin_amdgcn_global_load_lds( \
    (const __attribute__((address_space(1))) unsigned int*)(gp), \
    (__attribute__((address_space(3))) unsigned int*)(lp), 16, 0, 0)

#define LGKM_BAR() do { asm volatile("s_waitcnt lgkmcnt(0)" ::: "memory"); \
                        __builtin_amdgcn_s_barrier(); } while(0)

__device__ __forceinline__ unsigned short f2bf(float x){
  unsigned int u = __float_as_uint(x);
  u = (u + 0x7fffu + ((u >> 16) & 1u)) >> 16;   // RNE
  return (unsigned short)u;
}

__device__ __forceinline__ float wredsum(float v){
  v += __shfl_xor(v,32); v += __shfl_xor(v,16); v += __shfl_xor(v,8);
  v += __shfl_xor(v,4);  v += __shfl_xor(v,2);  v += __shfl_xor(v,1);
  return v;
}

// q[j] = probe . wq[j,:] + bq[j]
__global__ void k_q(const float* __restrict__ probe, const float* __restrict__ ipw,
                    const float* __restrict__ ipb, float* __restrict__ q){
  int tid = threadIdx.x, lane = tid & 63, w = tid >> 6;
  int j = blockIdx.x*4 + w;
  const float* wr = ipw + (size_t)j*E;
  float s = 0.f;
  #pragma unroll
  for (int t=0;t<18;++t){ int e = lane + 64*t; s = fmaf(probe[e], wr[e], s); }
  s = wredsum(s);
  if (lane==0) q[j] = s + ipb[j];
}

// qk[h][e] = sum_d q[h*72+d]*wk[h*72+d, e]  -> bf16 B-frag order:
// frag kk = e>>5, lane = ((e>>3)&3)*16 + h, j = e&7. cb[h] = q[h]·bk_h
__global__ void k_qk(const float* __restrict__ q, const float* __restrict__ ipw,
                     const float* __restrict__ ipb, unsigned short* __restrict__ qkfrag,
                     float* __restrict__ cb){
  int idx = blockIdx.x*256 + threadIdx.x;   // < H*E
  int h = idx / E, e = idx % E;
  float s = 0.f;
  #pragma unroll 8
  for (int d=0; d<HD; ++d)
    s = fmaf(q[h*HD+d], ipw[(size_t)(E + h*HD + d)*E + e], s);
  int kk = e >> 5, g = (e >> 3) & 3, j = e & 7;
  qkfrag[(size_t)kk*512 + (g*16 + h)*8 + j] = f2bf(s);
  if (idx < H){
    float c = 0.f;
    for (int d=0; d<HD; ++d) c = fmaf(q[idx*HD+d], ipb[E + idx*HD + d], c);
    cb[idx] = c;
  }
}

// ---------------- fused flash pass: MFMA scores + wave0 softmax + fp32 VALU PV.
// grid: 32 b x 16 slices (256 rows); block = 4 waves; 16 stages of 16 rows.
// LDS: double fp32 tile (block-XOR-swizzled via pre-swizzled global src),
//      D1 partials, f[16], wgt[16][16]. 152,896 B -> 1 block/CU.
__global__ __launch_bounds__(256) void k_fused(
    const float* __restrict__ hidden, const unsigned short* __restrict__ qkfrag,
    const float* __restrict__ cb, const int* __restrict__ mask,
    float* __restrict__ part, float* __restrict__ part_ml){
  __shared__ float smemf[38224];
  float* D1      = smemf + 36864;   // [4][16][17]
  float* f_lds   = smemf + 37952;   // [16]
  float* wgt_lds = smemf + 37968;   // [16][16]

  int tid = threadIdx.x, lane = tid & 63, w = tid >> 6;
  int b = blockIdx.x >> 4, sl = blockIdx.x & 15;
  int s0 = sl * 256;

  // qk B-frags in registers: wave w covers e in [288w, 288w+288)
  short8 qkf[9];
  {
    const short8* qf = (const short8*)qkfrag;
    #pragma unroll
    for (int kk=0;kk<9;++kk) qkf[kk] = qf[(9*w + kk)*64 + lane];
  }

  // staging source offsets (stage-invariant, swizzled): lds float idx
  // d = (w*18+i)*256 + lane*4 holds global float r*1152 + ((eb^ (r&7))<<3)+lo
  int soff[18];
  #pragma unroll
  for (int i=0;i<18;++i){
    int d = (w*18 + i)*256 + lane*4;
    int r = d / 1152;
    int o = d - r*1152;
    int eb = o >> 3, lo = o & 7;
    soff[i] = r*1152 + (((eb ^ (r & 7)) << 3) + lo);
  }

  float2 acc[4][9];
  #pragma unroll
  for (int j=0;j<4;++j)
    #pragma unroll
    for (int k=0;k<9;++k){ acc[j][k].x = 0.f; acc[j][k].y = 0.f; }

  float m = -INFINITY, lsum = 0.f;
  float scb = SCALE * cb[lane & 15];
  const float* hbase = hidden + ((size_t)b*S + s0)*E;
  const int* maskrow = mask + (size_t)b*S + s0;

  int rA = lane & 15, gA = lane >> 4;
  int ebA0 = w*36 + gA, rxA = rA & 7;
  int lb4 = lane >> 2, le = 2*(lane & 3);

  // prologue: stage 0 -> tile 0
  {
    const float* src = hbase;
    #pragma unroll
    for (int i=0;i<18;++i)
      GLOAD_LDS16(src + soff[i], smemf + (w*18 + i)*256);
  }

  for (int st=0; st<16; ++st){
    __syncthreads();                       // drains vmcnt: tile[st&1] ready
    float* tp = smemf + (st & 1)*18432;
    if (st+1 < 16){                        // prefetch into other buffer
      const float* src = hbase + (size_t)(st+1)*18432;
      float* dst = smemf + ((st+1) & 1)*18432;
      #pragma unroll
      for (int i=0;i<18;++i)
        GLOAD_LDS16(src + soff[i], dst + (w*18 + i)*256);
    }

    // ---- scores: 9 MFMA over this wave's e-quarter
    f32x4 d1 = {0.f,0.f,0.f,0.f};
    #pragma unroll
    for (int kk=0;kk<9;++kk){
      int idx = rA*1152 + (((ebA0 + 4*kk) ^ rxA) << 3);
      const float4 fa = *(const float4*)(tp + idx);
      const float4 fb = *(const float4*)(tp + idx + 4);
      short8 a;
      a[0]=(short)f2bf(fa.x); a[1]=(short)f2bf(fa.y);
      a[2]=(short)f2bf(fa.z); a[3]=(short)f2bf(fa.w);
      a[4]=(short)f2bf(fb.x); a[5]=(short)f2bf(fb.y);
      a[6]=(short)f2bf(fb.z); a[7]=(short)f2bf(fb.w);
      d1 = __builtin_amdgcn_mfma_f32_16x16x32_bf16(a, qkf[kk], d1, 0, 0, 0);
    }
    #pragma unroll
    for (int q=0;q<4;++q)
      D1[(w*16 + gA*4 + q)*17 + rA] = d1[q];

    LGKM_BAR();                            // D1 ready (lgkm only; vmcnt stays)

    if (w == 0){
      int hh = lane & 15, gg = lane >> 4;
      float v[4];
      #pragma unroll
      for (int q=0;q<4;++q){
        int R = gg*4 + q;
        float raw = D1[R*17+hh] + D1[(16+R)*17+hh]
                  + D1[(32+R)*17+hh] + D1[(48+R)*17+hh];
        int mv = maskrow[st*16 + R];
        v[q] = fmaf(raw, SCALE, scb) + (1.0f - (float)mv)*NEGF;
      }
      float sm = fmaxf(fmaxf(v[0],v[1]), fmaxf(v[2],v[3]));
      sm = fmaxf(sm, __shfl_xor(sm,16));
      sm = fmaxf(sm, __shfl_xor(sm,32));
      float f = 1.0f;
      if (__any(sm > m + 8.0f)){
        float mn = fmaxf(m, sm);
        f = __expf(m - mn);
        m = mn; lsum *= f;
      }
      if (lane < 16) f_lds[lane] = f;
      #pragma unroll
      for (int q=0;q<4;++q){
        float wq = __expf(v[q] - m);
        lsum += wq;
        wgt_lds[(gg*4+q)*16 + hh] = wq;
      }
    }

    LGKM_BAR();                            // wgt/f ready

    // ---- PV: fp32 accumulate, wave owns heads 4w..4w+3, lane e-slice {2l,2l+1}+128k
    {
      const float4 fv = *(const float4*)(f_lds + 4*w);
      if (fv.x!=1.f || fv.y!=1.f || fv.z!=1.f || fv.w!=1.f){
        #pragma unroll
        for (int k=0;k<9;++k){
          acc[0][k].x*=fv.x; acc[0][k].y*=fv.x;
          acc[1][k].x*=fv.y; acc[1][k].y*=fv.y;
          acc[2][k].x*=fv.z; acc[2][k].y*=fv.z;
          acc[3][k].x*=fv.w; acc[3][k].y*=fv.w;
        }
      }
      #pragma unroll
      for (int r2=0; r2<16; ++r2){
        const float4 wg = *(const float4*)(wgt_lds + r2*16 + 4*w);
        int rowbase = r2*1152 + ((lb4 ^ (r2 & 7)) << 3) + le;
        #pragma unroll
        for (int k=0;k<9;++k){
          const float2 hv = *(const float2*)(tp + rowbase + 128*k);
          acc[0][k].x = fmaf(wg.x, hv.x, acc[0][k].x); acc[0][k].y = fmaf(wg.x, hv.y, acc[0][k].y);
          acc[1][k].x = fmaf(wg.y, hv.x, acc[1][k].x); acc[1][k].y = fmaf(wg.y, hv.y, acc[1][k].y);
          acc[2][k].x = fmaf(wg.z, hv.x, acc[2][k].x); acc[2][k].y = fmaf(wg.z, hv.y, acc[2][k].y);
          acc[3][k].x = fmaf(wg.w, hv.x, acc[3][k].x); acc[3][k].y = fmaf(wg.w, hv.y, acc[3][k].y);
        }
      }
    }
    // next iteration's __syncthreads orders tile reuse + prefetch drain
  }

  if (w == 0){
    float lt = lsum + __shfl_xor(lsum, 16);
    lt += __shfl_xor(lt, 32);
    if (lane < 16){
      size_t o = ((size_t)(b*NSL + sl)*16 + lane)*2;
      part_ml[o] = m; part_ml[o+1] = lt;
    }
  }
  #pragma unroll
  for (int j=0;j<4;++j){
    float2* dst = (float2*)(part + ((size_t)(b*NSL + sl)*H + 4*w + j)*E);
    #pragma unroll
    for (int k=0;k<9;++k) dst[lane + 64*k] = acc[j][k];
  }
}

// combine slice-partials -> per-slice final scale = exp(m_sl - M)/L_total
__global__ void k_mlcomb(const float* __restrict__ part_ml, float* __restrict__ scale){
  int t = threadIdx.x;            // 512 = 32*16
  int b = t >> 4, h = t & 15;
  float M = -INFINITY, L = 0.f;
  for (int c = 0; c < NSL; ++c){
    size_t o = ((size_t)(b*NSL + c)*16 + h)*2;
    float om = part_ml[o], ol = part_ml[o+1];
    float nm = fmaxf(M, om);
    L = L*__expf(M - nm) + ol*__expf(om - nm);
    M = nm;
  }
  float invL = 1.0f / L;
  for (int c = 0; c < NSL; ++c){
    size_t o = ((size_t)(b*NSL + c)*16 + h)*2;
    scale[(size_t)(b*NSL + c)*16 + h] = __expf(part_ml[o] - M) * invL;
  }
}

// ctx[b][h][e] = sum_sl part[b][sl][h][e] * scale[b][sl][h]
__global__ void k_ctxred(const float* __restrict__ part, const float* __restrict__ scale,
                         float* __restrict__ ctx){
  int idx = blockIdx.x*256 + threadIdx.x;  // < B*H*E
  int b = idx / (H*E); int he = idx % (H*E); int h = he / E;
  float s = 0.f;
  #pragma unroll 4
  for (int sl=0; sl<NSL; ++sl)
    s = fmaf(part[(size_t)(b*NSL+sl)*H*E + he], scale[(size_t)(b*NSL+sl)*16 + h], s);
  ctx[idx] = s;
}

// pooled[b, j] = wv[j,:]·ctx[b, j/72, :] + bv[j]
__global__ void k_pool(const float* __restrict__ ctx, const float* __restrict__ ipw,
                       const float* __restrict__ ipb, float* __restrict__ pooled){
  int tid = threadIdx.x, lane = tid & 63, w = tid >> 6;
  int j = blockIdx.x*4 + w;
  int h = j / HD;
  const float* wr = ipw + (size_t)2*E*E + (size_t)j*E;
  float acc[32];
  #pragma unroll
  for (int b_=0;b_<32;++b_) acc[b_]=0.f;
  #pragma unroll
  for (int t=0;t<18;++t){
    int e = lane + 64*t;
    float wv = wr[e];
    #pragma unroll
    for (int b_=0;b_<32;++b_)
      acc[b_] = fmaf(wv, ctx[(size_t)(b_*H + h)*E + e], acc[b_]);
  }
  #pragma unroll
  for (int b_=0;b_<32;++b_){
    float s = wredsum(acc[b_]);
    if (lane==b_) pooled[(size_t)b_*E + j] = s + ipb[2*E + j];
  }
}

__global__ void k_outproj(const float* __restrict__ pooled, const float* __restrict__ ow,
                          const float* __restrict__ ob, float* __restrict__ resid){
  int tid = threadIdx.x, lane = tid & 63, w = tid >> 6;
  int i = blockIdx.x*4 + w;
  const float* wr = ow + (size_t)i*E;
  float acc[32];
  #pragma unroll
  for (int b_=0;b_<32;++b_) acc[b_]=0.f;
  #pragma unroll
  for (int t=0;t<18;++t){
    int e = lane + 64*t;
    float wv = wr[e];
    #pragma unroll
    for (int b_=0;b_<32;++b_)
      acc[b_] = fmaf(wv, pooled[(size_t)b_*E + e], acc[b_]);
  }
  #pragma unroll
  for (int b_=0;b_<32;++b_){
    float s = wredsum(acc[b_]);
    if (lane==b_) resid[(size_t)b_*E + i] = s + ob[i];
  }
}

__global__ void k_ln(const float* __restrict__ resid, const float* __restrict__ g,
                     const float* __restrict__ be, float* __restrict__ x){
  __shared__ float red[8];
  int b = blockIdx.x, tid = threadIdx.x, lane = tid & 63, w = tid >> 6;
  const float* r = resid + (size_t)b*E;
  float s = 0.f, s2 = 0.f;
  for (int e=tid; e<E; e+=256){ float v = r[e]; s += v; s2 = fmaf(v,v,s2); }
  s = wredsum(s); s2 = wredsum(s2);
  if (lane==0){ red[w]=s; red[4+w]=s2; }
  __syncthreads();
  float S1 = red[0]+red[1]+red[2]+red[3];
  float S2 = red[4]+red[5]+red[6]+red[7];
  float mu  = S1*(1.0f/E);
  float var = S2*(1.0f/E) - mu*mu;
  float inv = rsqrtf(var + 1e-6f);
  for (int e=tid; e<E; e+=256){
    float v = (r[e]-mu)*inv;
    x[(size_t)b*E + e] = v*g[e] + be[e];
  }
}

__device__ __forceinline__ float gelu_tanh(float u){
  float u3 = u*u*u;
  float t = tanhf(0.7978845608028654f*(u + 0.044715f*u3));
  return 0.5f*u*(1.0f+t);
}

__global__ __launch_bounds__(256) void k_fc1(
    const float* __restrict__ x, const float* __restrict__ w1,
    const float* __restrict__ b1, float* __restrict__ h1){
  int tid = threadIdx.x, lane = tid & 63, w = tid >> 6;
  int wid = blockIdx.x*4 + w;      // < 2152
  int i0 = wid*2;
  float acc[2][32];
  #pragma unroll
  for (int ii=0;ii<2;++ii)
    #pragma unroll
    for (int b_=0;b_<32;++b_) acc[ii][b_]=0.f;
  #pragma unroll
  for (int t=0;t<18;++t){
    int e = lane + 64*t;
    float f0 = w1[(size_t)i0*E + e];
    float f1 = w1[(size_t)(i0+1)*E + e];
    #pragma unroll
    for (int b_=0;b_<32;++b_){
      float xv = x[(size_t)b_*E + e];
      acc[0][b_] = fmaf(f0, xv, acc[0][b_]);
      acc[1][b_] = fmaf(f1, xv, acc[1][b_]);
    }
  }
  #pragma unroll
  for (int ii=0;ii<2;++ii)
    #pragma unroll
    for (int b_=0;b_<32;++b_){
      float s = wredsum(acc[ii][b_]);
      if (lane==b_) h1[(size_t)b_*IDIM + i0 + ii] = gelu_tanh(s + b1[i0+ii]);
    }
}

__global__ __launch_bounds__(256) void k_fc2(
    const float* __restrict__ h1, const float* __restrict__ w2,
    const float* __restrict__ b2, const float* __restrict__ resid,
    float* __restrict__ out){
  int tid = threadIdx.x, lane = tid & 63, w = tid >> 6;
  int wid = blockIdx.x*4 + w;      // < 576
  int i0 = wid*2;
  float acc[2][32];
  #pragma unroll
  for (int ii=0;ii<2;++ii)
    #pragma unroll
    for (int b_=0;b_<32;++b_) acc[ii][b_]=0.f;
  #pragma unroll 2
  for (int t=0;t<68;++t){
    int e = lane + 64*t;
    if (e < IDIM){
      float f0 = w2[(size_t)i0*IDIM + e];
      float f1 = w2[(size_t)(i0+1)*IDIM + e];
      #pragma unroll
      for (int b_=0;b_<32;++b_){
        float hvv = h1[(size_t)b_*IDIM + e];
        acc[0][b_] = fmaf(f0, hvv, acc[0][b_]);
        acc[1][b_] = fmaf(f1, hvv, acc[1][b_]);
      }
    }
  }
  #pragma unroll
  for (int ii=0;ii<2;++ii)
    #pragma unroll
    for (int b_=0;b_<32;++b_){
      float s = wredsum(acc[ii][b_]);
      if (lane==b_){
        int i = i0 + ii;
        out[(size_t)b_*E + i] = resid[(size_t)b_*E + i] + s + b2[i];
      }
    }
}

extern "C" void kernel_launch(void* const* d_in, const int* in_sizes, int n_in,
                              void* d_out, int out_size, void* d_ws, size_t ws_size,
                              hipStream_t stream){
  const float* hidden = (const float*)d_in[0];
  const int*   mask   = (const int*)d_in[1];
  const float* probe  = (const float*)d_in[2];
  const float* ipw    = (const float*)d_in[3];
  const float* ipb    = (const float*)d_in[4];
  const float* ow     = (const float*)d_in[5];
  const float* ob     = (const float*)d_in[6];
  const float* ln_g   = (const float*)d_in[7];
  const float* ln_b   = (const float*)d_in[8];
  const float* w1     = (const float*)d_in[9];
  const float* b1     = (const float*)d_in[10];
  const float* w2     = (const float*)d_in[11];
  const float* b2     = (const float*)d_in[12];
  float* out = (float*)d_out;
  float* ws  = (float*)d_ws;

  size_t off = 0;
  float* q  = ws + off; off += E;                       // 1152
  float* cb = ws + off; off += 16;                      // 1168 (16B aligned x4)
  unsigned short* qkfrag = (unsigned short*)(ws + off); off += 9216;  // 36*64*8 bf16
  float* part_ml = ws + off; off += 32*NSL*16*2;
  float* scale   = ws + off; off += 32*NSL*16;
  float* part    = ws + off; off += (size_t)B*NSL*H*E;  // 37.7 MB
  float* ctx     = ws + off; off += (size_t)B*H*E;
  float* pooled  = ws + off; off += (size_t)B*E;
  float* resid   = ws + off; off += (size_t)B*E;
  float* x       = ws + off; off += (size_t)B*E;
  float* h1      = ws + off;

  k_q       <<<288, 256, 0, stream>>>(probe, ipw, ipb, q);
  k_qk      <<<72, 256, 0, stream>>>(q, ipw, ipb, qkfrag, cb);
  k_fused   <<<B*NSL, 256, 0, stream>>>(hidden, qkfrag, cb, mask, part, part_ml);
  k_mlcomb  <<<1, 512, 0, stream>>>(part_ml, scale);
  k_ctxred  <<<2304, 256, 0, stream>>>(part, scale, ctx);
  k_pool    <<<288, 256, 0, stream>>>(ctx, ipw, ipb, pooled);
  k_outproj <<<288, 256, 0, stream>>>(pooled, ow, ob, resid);
  k_ln      <<<32, 256, 0, stream>>>(resid, ln_g, ln_b, x);
  k_fc1     <<<538, 256, 0, stream>>>(x, w1, b1, h1);
  k_fc2     <<<144, 256, 0, stream>>>(h1, w2, b2, resid, out);
}

// Round 7
// 1072.922 us; speedup vs baseline: 1.1306x; 1.0161x over previous
//
#include <hip/hip_runtime.h>
#include <math.h>

#define E 1152
#define H 16
#define HD 72
#define B 32
#define S 4096
#define IDIM 4304
#define NSL 16

#define NEGF (-3.402823466e38f)
#define SCALE 0.1178511301977579f  // 1/sqrt(72)

typedef short short8 __attribute__((ext_vector_type(8)));
typedef float f32x4 __attribute__((ext_vector_type(4)));
typedef unsigned int uint4v __attribute__((ext_vector_type(4)));

#define GLOAD_LDS16(gp, lp) __builtin_amdgcn_global_load_lds( \
    (const __attribute__((address_space(1))) unsigned int*)(gp), \
    (__attribute__((address_space(3))) unsigned int*)(lp), 16, 0, 0)

#define LGKM_BAR() do { asm volatile("s_waitcnt lgkmcnt(0)" ::: "memory"); \
                        __builtin_amdgcn_s_barrier(); } while(0)

__device__ __forceinline__ unsigned int cvtpk_bf16(float lo, float hi){
  unsigned int r;
  asm("v_cvt_pk_bf16_f32 %0, %1, %2" : "=v"(r) : "v"(lo), "v"(hi));
  return r;
}

__device__ __forceinline__ unsigned short f2bf(float x){
  unsigned int u = __float_as_uint(x);
  u = (u + 0x7fffu + ((u >> 16) & 1u)) >> 16;   // RNE
  return (unsigned short)u;
}

__device__ __forceinline__ float wredsum(float v){
  v += __shfl_xor(v,32); v += __shfl_xor(v,16); v += __shfl_xor(v,8);
  v += __shfl_xor(v,4);  v += __shfl_xor(v,2);  v += __shfl_xor(v,1);
  return v;
}

// q[j] = probe . wq[j,:] + bq[j]
__global__ void k_q(const float* __restrict__ probe, const float* __restrict__ ipw,
                    const float* __restrict__ ipb, float* __restrict__ q){
  int tid = threadIdx.x, lane = tid & 63, w = tid >> 6;
  int j = blockIdx.x*4 + w;
  const float* wr = ipw + (size_t)j*E;
  float s = 0.f;
  #pragma unroll
  for (int t=0;t<18;++t){ int e = lane + 64*t; s = fmaf(probe[e], wr[e], s); }
  s = wredsum(s);
  if (lane==0) q[j] = s + ipb[j];
}

// qk[h][e] -> bf16 B-frag order: kk = e>>5, lane = ((e>>3)&3)*16 + h, j = e&7
__global__ void k_qk(const float* __restrict__ q, const float* __restrict__ ipw,
                     const float* __restrict__ ipb, unsigned short* __restrict__ qkfrag,
                     float* __restrict__ cb){
  int idx = blockIdx.x*256 + threadIdx.x;   // < H*E
  int h = idx / E, e = idx % E;
  float s = 0.f;
  #pragma unroll 8
  for (int d=0; d<HD; ++d)
    s = fmaf(q[h*HD+d], ipw[(size_t)(E + h*HD + d)*E + e], s);
  int kk = e >> 5, g = (e >> 3) & 3, j = e & 7;
  qkfrag[(size_t)kk*512 + (g*16 + h)*8 + j] = f2bf(s);
  if (idx < H){
    float c = 0.f;
    for (int d=0; d<HD; ++d) c = fmaf(q[idx*HD+d], ipb[E + idx*HD + d], c);
    cb[idx] = c;
  }
}

// ---------------- fused flash pass: MFMA scores + wave0 softmax + fp32 VALU PV.
// grid: 32 b x 16 slices (256 rows); block = 4 waves; 16 stages of 16 rows.
// 4-float-granularity XOR swizzle (fb ^ (r&7)) -> all 32 banks used.
// Mask preloaded to LDS: no vmcnt-draining global loads inside the loop.
__global__ __launch_bounds__(256) void k_fused(
    const float* __restrict__ hidden, const unsigned short* __restrict__ qkfrag,
    const float* __restrict__ cb, const int* __restrict__ mask,
    float* __restrict__ part, float* __restrict__ part_ml){
  __shared__ float smemf[38480];
  float* D1       = smemf + 36864;   // [4][16][17] = 1088
  float* f_lds    = smemf + 37952;   // [16]
  float* wgt_lds  = smemf + 37968;   // [16][16]
  float* mask_lds = smemf + 38224;   // [256] additive mask

  int tid = threadIdx.x, lane = tid & 63, w = tid >> 6;
  int b = blockIdx.x >> 4, sl = blockIdx.x & 15;
  int s0 = sl * 256;

  // preload additive mask for this block's 256 rows (single vmcnt event)
  mask_lds[tid] = (1.0f - (float)mask[(size_t)b*S + s0 + tid]) * NEGF;

  // qk B-frags in registers: wave w covers e in [288w, 288w+288)
  short8 qkf[9];
  {
    const short8* qf = (const short8*)qkfrag;
    #pragma unroll
    for (int kk=0;kk<9;++kk) qkf[kk] = qf[(9*w + kk)*64 + lane];
  }

  // staging source offsets (4-float swizzle): lds float idx
  // d = (w*18+i)*256 + lane*4 holds global float r*1152 + ((fb ^ (r&7))<<2)
  int soff[18];
  #pragma unroll
  for (int i=0;i<18;++i){
    int d = (w*18 + i)*256 + lane*4;
    int r = d / 1152;
    int o = d - r*1152;
    int fb = o >> 2;
    soff[i] = r*1152 + ((fb ^ (r & 7)) << 2);
  }

  float2 acc[4][9];
  #pragma unroll
  for (int j=0;j<4;++j)
    #pragma unroll
    for (int k=0;k<9;++k){ acc[j][k].x = 0.f; acc[j][k].y = 0.f; }

  float m = -INFINITY, lsum = 0.f;
  float scb = SCALE * cb[lane & 15];
  const float* hbase = hidden + ((size_t)b*S + s0)*E;

  int rA = lane & 15, gA = lane >> 4, rxA = rA & 7;
  int fbA0 = 72*w + 2*gA;            // + 8*kk per step
  int lb4 = lane >> 2, le = 2*(lane & 3);
  int fbP0 = 2*lb4 + (le >> 2), lo2 = le & 3;

  // prologue: stage 0 -> tile 0
  {
    const float* src = hbase;
    #pragma unroll
    for (int i=0;i<18;++i)
      GLOAD_LDS16(src + soff[i], smemf + (w*18 + i)*256);
  }

  for (int st=0; st<16; ++st){
    __syncthreads();                       // drains vmcnt: tile[st&1] ready
    float* tp = smemf + (st & 1)*18432;
    if (st+1 < 16){                        // prefetch into other buffer
      const float* src = hbase + (size_t)(st+1)*18432;
      float* dst = smemf + ((st+1) & 1)*18432;
      #pragma unroll
      for (int i=0;i<18;++i)
        GLOAD_LDS16(src + soff[i], dst + (w*18 + i)*256);
    }

    // ---- scores: 9 MFMA over this wave's e-quarter
    f32x4 d1 = {0.f,0.f,0.f,0.f};
    #pragma unroll
    for (int kk=0;kk<9;++kk){
      int fb0 = fbA0 + 8*kk;
      const float4 fa = *(const float4*)(tp + rA*1152 + ((fb0     ^ rxA) << 2));
      const float4 fc = *(const float4*)(tp + rA*1152 + (((fb0+1) ^ rxA) << 2));
      uint4v u;
      u[0] = cvtpk_bf16(fa.x, fa.y);
      u[1] = cvtpk_bf16(fa.z, fa.w);
      u[2] = cvtpk_bf16(fc.x, fc.y);
      u[3] = cvtpk_bf16(fc.z, fc.w);
      d1 = __builtin_amdgcn_mfma_f32_16x16x32_bf16(
             __builtin_bit_cast(short8, u), qkf[kk], d1, 0, 0, 0);
    }
    #pragma unroll
    for (int q=0;q<4;++q)
      D1[(w*16 + gA*4 + q)*17 + rA] = d1[q];

    LGKM_BAR();                            // D1 ready (lgkm only; vmcnt stays)

    if (w == 0){
      int hh = lane & 15, gg = lane >> 4;
      float v[4];
      #pragma unroll
      for (int q=0;q<4;++q){
        int R = gg*4 + q;
        float raw = D1[R*17+hh] + D1[(16+R)*17+hh]
                  + D1[(32+R)*17+hh] + D1[(48+R)*17+hh];
        v[q] = fmaf(raw, SCALE, scb) + mask_lds[st*16 + R];
      }
      float sm = fmaxf(fmaxf(v[0],v[1]), fmaxf(v[2],v[3]));
      sm = fmaxf(sm, __shfl_xor(sm,16));
      sm = fmaxf(sm, __shfl_xor(sm,32));
      float f = 1.0f;
      if (__any(sm > m + 8.0f)){
        float mn = fmaxf(m, sm);
        f = __expf(m - mn);
        m = mn; lsum *= f;
      }
      if (lane < 16) f_lds[lane] = f;
      #pragma unroll
      for (int q=0;q<4;++q){
        float wq = __expf(v[q] - m);
        lsum += wq;
        wgt_lds[(gg*4+q)*16 + hh] = wq;
      }
    }

    LGKM_BAR();                            // wgt/f ready

    // ---- PV: fp32 accumulate, wave owns heads 4w..4w+3
    {
      const float4 fv = *(const float4*)(f_lds + 4*w);
      if (fv.x!=1.f || fv.y!=1.f || fv.z!=1.f || fv.w!=1.f){
        #pragma unroll
        for (int k=0;k<9;++k){
          acc[0][k].x*=fv.x; acc[0][k].y*=fv.x;
          acc[1][k].x*=fv.y; acc[1][k].y*=fv.y;
          acc[2][k].x*=fv.z; acc[2][k].y*=fv.z;
          acc[3][k].x*=fv.w; acc[3][k].y*=fv.w;
        }
      }
      #pragma unroll
      for (int r2=0; r2<16; ++r2){
        const float4 wg = *(const float4*)(wgt_lds + r2*16 + 4*w);
        int rx2 = r2 & 7;
        int rowb = r2*1152;
        #pragma unroll
        for (int k=0;k<9;++k){
          const float2 hv = *(const float2*)(tp + rowb + (((fbP0 + 32*k) ^ rx2) << 2) + lo2);
          acc[0][k].x = fmaf(wg.x, hv.x, acc[0][k].x); acc[0][k].y = fmaf(wg.x, hv.y, acc[0][k].y);
          acc[1][k].x = fmaf(wg.y, hv.x, acc[1][k].x); acc[1][k].y = fmaf(wg.y, hv.y, acc[1][k].y);
          acc[2][k].x = fmaf(wg.z, hv.x, acc[2][k].x); acc[2][k].y = fmaf(wg.z, hv.y, acc[2][k].y);
          acc[3][k].x = fmaf(wg.w, hv.x, acc[3][k].x); acc[3][k].y = fmaf(wg.w, hv.y, acc[3][k].y);
        }
      }
    }
  }

  if (w == 0){
    float lt = lsum + __shfl_xor(lsum, 16);
    lt += __shfl_xor(lt, 32);
    if (lane < 16){
      size_t o = ((size_t)(b*NSL + sl)*16 + lane)*2;
      part_ml[o] = m; part_ml[o+1] = lt;
    }
  }
  #pragma unroll
  for (int j=0;j<4;++j){
    float2* dst = (float2*)(part + ((size_t)(b*NSL + sl)*H + 4*w + j)*E);
    #pragma unroll
    for (int k=0;k<9;++k) dst[lane + 64*k] = acc[j][k];
  }
}

// ctx[b][h][e] = sum_sl part[b][sl][h][e] * exp(m_sl - M) / L   (mlcomb folded in)
__global__ void k_ctxred(const float* __restrict__ part, const float* __restrict__ part_ml,
                         float* __restrict__ ctx){
  int idx = blockIdx.x*256 + threadIdx.x;  // < B*H*E
  int b = idx / (H*E); int he = idx % (H*E); int h = he / E;
  float M = -INFINITY, L = 0.f;
  #pragma unroll 4
  for (int c = 0; c < NSL; ++c){
    size_t o = ((size_t)(b*NSL + c)*16 + h)*2;
    float om = part_ml[o], ol = part_ml[o+1];
    float nm = fmaxf(M, om);
    L = L*__expf(M - nm) + ol*__expf(om - nm);
    M = nm;
  }
  float invL = 1.0f / L;
  float s = 0.f;
  #pragma unroll 4
  for (int sl=0; sl<NSL; ++sl){
    float scl = __expf(part_ml[((size_t)(b*NSL + sl)*16 + h)*2] - M) * invL;
    s = fmaf(part[(size_t)(b*NSL+sl)*H*E + he], scl, s);
  }
  ctx[idx] = s;
}

// pooled[b, j] = wv[j,:]·ctx[b, j/72, :] + bv[j]
__global__ void k_pool(const float* __restrict__ ctx, const float* __restrict__ ipw,
                       const float* __restrict__ ipb, float* __restrict__ pooled){
  int tid = threadIdx.x, lane = tid & 63, w = tid >> 6;
  int j = blockIdx.x*4 + w;
  int h = j / HD;
  const float* wr = ipw + (size_t)2*E*E + (size_t)j*E;
  float acc[32];
  #pragma unroll
  for (int b_=0;b_<32;++b_) acc[b_]=0.f;
  #pragma unroll
  for (int t=0;t<18;++t){
    int e = lane + 64*t;
    float wv = wr[e];
    #pragma unroll
    for (int b_=0;b_<32;++b_)
      acc[b_] = fmaf(wv, ctx[(size_t)(b_*H + h)*E + e], acc[b_]);
  }
  #pragma unroll
  for (int b_=0;b_<32;++b_){
    float s = wredsum(acc[b_]);
    if (lane==b_) pooled[(size_t)b_*E + j] = s + ipb[2*E + j];
  }
}

__global__ void k_outproj(const float* __restrict__ pooled, const float* __restrict__ ow,
                          const float* __restrict__ ob, float* __restrict__ resid){
  int tid = threadIdx.x, lane = tid & 63, w = tid >> 6;
  int i = blockIdx.x*4 + w;
  const float* wr = ow + (size_t)i*E;
  float acc[32];
  #pragma unroll
  for (int b_=0;b_<32;++b_) acc[b_]=0.f;
  #pragma unroll
  for (int t=0;t<18;++t){
    int e = lane + 64*t;
    float wv = wr[e];
    #pragma unroll
    for (int b_=0;b_<32;++b_)
      acc[b_] = fmaf(wv, pooled[(size_t)b_*E + e], acc[b_]);
  }
  #pragma unroll
  for (int b_=0;b_<32;++b_){
    float s = wredsum(acc[b_]);
    if (lane==b_) resid[(size_t)b_*E + i] = s + ob[i];
  }
}

__global__ void k_ln(const float* __restrict__ resid, const float* __restrict__ g,
                     const float* __restrict__ be, float* __restrict__ x){
  __shared__ float red[8];
  int b = blockIdx.x, tid = threadIdx.x, lane = tid & 63, w = tid >> 6;
  const float* r = resid + (size_t)b*E;
  float s = 0.f, s2 = 0.f;
  for (int e=tid; e<E; e+=256){ float v = r[e]; s += v; s2 = fmaf(v,v,s2); }
  s = wredsum(s); s2 = wredsum(s2);
  if (lane==0){ red[w]=s; red[4+w]=s2; }
  __syncthreads();
  float S1 = red[0]+red[1]+red[2]+red[3];
  float S2 = red[4]+red[5]+red[6]+red[7];
  float mu  = S1*(1.0f/E);
  float var = S2*(1.0f/E) - mu*mu;
  float inv = rsqrtf(var + 1e-6f);
  for (int e=tid; e<E; e+=256){
    float v = (r[e]-mu)*inv;
    x[(size_t)b*E + e] = v*g[e] + be[e];
  }
}

__device__ __forceinline__ float gelu_tanh(float u){
  float u3 = u*u*u;
  float t = tanhf(0.7978845608028654f*(u + 0.044715f*u3));
  return 0.5f*u*(1.0f+t);
}

__global__ __launch_bounds__(256) void k_fc1(
    const float* __restrict__ x, const float* __restrict__ w1,
    const float* __restrict__ b1, float* __restrict__ h1){
  int tid = threadIdx.x, lane = tid & 63, w = tid >> 6;
  int wid = blockIdx.x*4 + w;      // < 2152
  int i0 = wid*2;
  float acc[2][32];
  #pragma unroll
  for (int ii=0;ii<2;++ii)
    #pragma unroll
    for (int b_=0;b_<32;++b_) acc[ii][b_]=0.f;
  #pragma unroll
  for (int t=0;t<18;++t){
    int e = lane + 64*t;
    float f0 = w1[(size_t)i0*E + e];
    float f1 = w1[(size_t)(i0+1)*E + e];
    #pragma unroll
    for (int b_=0;b_<32;++b_){
      float xv = x[(size_t)b_*E + e];
      acc[0][b_] = fmaf(f0, xv, acc[0][b_]);
      acc[1][b_] = fmaf(f1, xv, acc[1][b_]);
    }
  }
  #pragma unroll
  for (int ii=0;ii<2;++ii)
    #pragma unroll
    for (int b_=0;b_<32;++b_){
      float s = wredsum(acc[ii][b_]);
      if (lane==b_) h1[(size_t)b_*IDIM + i0 + ii] = gelu_tanh(s + b1[i0+ii]);
    }
}

__global__ __launch_bounds__(256) void k_fc2(
    const float* __restrict__ h1, const float* __restrict__ w2,
    const float* __restrict__ b2, const float* __restrict__ resid,
    float* __restrict__ out){
  int tid = threadIdx.x, lane = tid & 63, w = tid >> 6;
  int wid = blockIdx.x*4 + w;      // < 576
  int i0 = wid*2;
  float acc[2][32];
  #pragma unroll
  for (int ii=0;ii<2;++ii)
    #pragma unroll
    for (int b_=0;b_<32;++b_) acc[ii][b_]=0.f;
  #pragma unroll 2
  for (int t=0;t<68;++t){
    int e = lane + 64*t;
    if (e < IDIM){
      float f0 = w2[(size_t)i0*IDIM + e];
      float f1 = w2[(size_t)(i0+1)*IDIM + e];
      #pragma unroll
      for (int b_=0;b_<32;++b_){
        float hvv = h1[(size_t)b_*IDIM + e];
        acc[0][b_] = fmaf(f0, hvv, acc[0][b_]);
        acc[1][b_] = fmaf(f1, hvv, acc[1][b_]);
      }
    }
  }
  #pragma unroll
  for (int ii=0;ii<2;++ii)
    #pragma unroll
    for (int b_=0;b_<32;++b_){
      float s = wredsum(acc[ii][b_]);
      if (lane==b_){
        int i = i0 + ii;
        out[(size_t)b_*E + i] = resid[(size_t)b_*E + i] + s + b2[i];
      }
    }
}

extern "C" void kernel_launch(void* const* d_in, const int* in_sizes, int n_in,
                              void* d_out, int out_size, void* d_ws, size_t ws_size,
                              hipStream_t stream){
  const float* hidden = (const float*)d_in[0];
  const int*   mask   = (const int*)d_in[1];
  const float* probe  = (const float*)d_in[2];
  const float* ipw    = (const float*)d_in[3];
  const float* ipb    = (const float*)d_in[4];
  const float* ow     = (const float*)d_in[5];
  const float* ob     = (const float*)d_in[6];
  const float* ln_g   = (const float*)d_in[7];
  const float* ln_b   = (const float*)d_in[8];
  const float* w1     = (const float*)d_in[9];
  const float* b1     = (const float*)d_in[10];
  const float* w2     = (const float*)d_in[11];
  const float* b2     = (const float*)d_in[12];
  float* out = (float*)d_out;
  float* ws  = (float*)d_ws;

  size_t off = 0;
  float* q  = ws + off; off += E;                       // 1152
  float* cb = ws + off; off += 16;
  unsigned short* qkfrag = (unsigned short*)(ws + off); off += 9216;  // 36*64*8 bf16
  float* part_ml = ws + off; off += 32*NSL*16*2;
  float* part    = ws + off; off += (size_t)B*NSL*H*E;  // 37.7 MB
  float* ctx     = ws + off; off += (size_t)B*H*E;
  float* pooled  = ws + off; off += (size_t)B*E;
  float* resid   = ws + off; off += (size_t)B*E;
  float* x       = ws + off; off += (size_t)B*E;
  float* h1      = ws + off;

  k_q       <<<288, 256, 0, stream>>>(probe, ipw, ipb, q);
  k_qk      <<<72, 256, 0, stream>>>(q, ipw, ipb, qkfrag, cb);
  k_fused   <<<B*NSL, 256, 0, stream>>>(hidden, qkfrag, cb, mask, part, part_ml);
  k_ctxred  <<<2304, 256, 0, stream>>>(part, part_ml, ctx);
  k_pool    <<<288, 256, 0, stream>>>(ctx, ipw, ipb, pooled);
  k_outproj <<<288, 256, 0, stream>>>(pooled, ow, ob, resid);
  k_ln      <<<32, 256, 0, stream>>>(resid, ln_g, ln_b, x);
  k_fc1     <<<538, 256, 0, stream>>>(x, w1, b1, h1);
  k_fc2     <<<144, 256, 0, stream>>>(h1, w2, b2, resid, out);
}

// Round 8
// 837.062 us; speedup vs baseline: 1.4491x; 1.2818x over previous
//
#include <hip/hip_runtime.h>
#include <math.h>

#define E 1152
#define H 16
#define HD 72
#define B 32
#define S 4096
#define IDIM 4304
#define NSL 16

#define NEGF (-3.402823466e38f)
#define SCALE 0.1178511301977579f  // 1/sqrt(72)

typedef short short8 __attribute__((ext_vector_type(8)));
typedef float f32x4 __attribute__((ext_vector_type(4)));
typedef unsigned int uint4v __attribute__((ext_vector_type(4)));

#define GLOAD_LDS16(gp, lp) __builtin_amdgcn_global_load_lds( \
    (const __attribute__((address_space(1))) unsigned int*)(gp), \
    (__attribute__((address_space(3))) unsigned int*)(lp), 16, 0, 0)

#define LGKM_BAR() do { asm volatile("s_waitcnt lgkmcnt(0)" ::: "memory"); \
                        __builtin_amdgcn_s_barrier(); } while(0)

__device__ __forceinline__ unsigned int cvtpk_bf16(float lo, float hi){
  unsigned int r;
  asm("v_cvt_pk_bf16_f32 %0, %1, %2" : "=v"(r) : "v"(lo), "v"(hi));
  return r;
}

__device__ __forceinline__ unsigned short f2bf(float x){
  unsigned int u = __float_as_uint(x);
  u = (u + 0x7fffu + ((u >> 16) & 1u)) >> 16;   // RNE
  return (unsigned short)u;
}

__device__ __forceinline__ float wredsum(float v){
  v += __shfl_xor(v,32); v += __shfl_xor(v,16); v += __shfl_xor(v,8);
  v += __shfl_xor(v,4);  v += __shfl_xor(v,2);  v += __shfl_xor(v,1);
  return v;
}

// q[j] = probe . wq[j,:] + bq[j]   (float2 loads)
__global__ void k_q(const float* __restrict__ probe, const float* __restrict__ ipw,
                    const float* __restrict__ ipb, float* __restrict__ q){
  int tid = threadIdx.x, lane = tid & 63, w = tid >> 6;
  int j = blockIdx.x*4 + w;
  const float2* wr = (const float2*)(ipw + (size_t)j*E);
  const float2* pr = (const float2*)probe;
  float s = 0.f;
  #pragma unroll
  for (int t=0;t<9;++t){
    int e2 = lane + 64*t;
    float2 a = pr[e2], b = wr[e2];
    s = fmaf(a.x, b.x, fmaf(a.y, b.y, s));
  }
  s = wredsum(s);
  if (lane==0) q[j] = s + ipb[j];
}

// qk[h][e] -> bf16 B-frag order: kk = e>>5, lane = ((e>>3)&3)*16 + h, j = e&7
__global__ void k_qk(const float* __restrict__ q, const float* __restrict__ ipw,
                     const float* __restrict__ ipb, unsigned short* __restrict__ qkfrag,
                     float* __restrict__ cb){
  int idx = blockIdx.x*256 + threadIdx.x;   // < H*E
  int h = idx / E, e = idx % E;
  float s = 0.f;
  #pragma unroll 8
  for (int d=0; d<HD; ++d)
    s = fmaf(q[h*HD+d], ipw[(size_t)(E + h*HD + d)*E + e], s);
  int kk = e >> 5, g = (e >> 3) & 3, j = e & 7;
  qkfrag[(size_t)kk*512 + (g*16 + h)*8 + j] = f2bf(s);
  if (idx < H){
    float c = 0.f;
    for (int d=0; d<HD; ++d) c = fmaf(q[idx*HD+d], ipb[E + idx*HD + d], c);
    cb[idx] = c;
  }
}

// ---------------- fused flash pass (unchanged from R7): MFMA scores +
// wave0 softmax + fp32 VALU PV, dbuf LDS, mask preloaded.
__global__ __launch_bounds__(256) void k_fused(
    const float* __restrict__ hidden, const unsigned short* __restrict__ qkfrag,
    const float* __restrict__ cb, const int* __restrict__ mask,
    float* __restrict__ part, float* __restrict__ part_ml){
  __shared__ float smemf[38480];
  float* D1       = smemf + 36864;   // [4][16][17] = 1088
  float* f_lds    = smemf + 37952;   // [16]
  float* wgt_lds  = smemf + 37968;   // [16][16]
  float* mask_lds = smemf + 38224;   // [256] additive mask

  int tid = threadIdx.x, lane = tid & 63, w = tid >> 6;
  int b = blockIdx.x >> 4, sl = blockIdx.x & 15;
  int s0 = sl * 256;

  mask_lds[tid] = (1.0f - (float)mask[(size_t)b*S + s0 + tid]) * NEGF;

  short8 qkf[9];
  {
    const short8* qf = (const short8*)qkfrag;
    #pragma unroll
    for (int kk=0;kk<9;++kk) qkf[kk] = qf[(9*w + kk)*64 + lane];
  }

  int soff[18];
  #pragma unroll
  for (int i=0;i<18;++i){
    int d = (w*18 + i)*256 + lane*4;
    int r = d / 1152;
    int o = d - r*1152;
    int fb = o >> 2;
    soff[i] = r*1152 + ((fb ^ (r & 7)) << 2);
  }

  float2 acc[4][9];
  #pragma unroll
  for (int j=0;j<4;++j)
    #pragma unroll
    for (int k=0;k<9;++k){ acc[j][k].x = 0.f; acc[j][k].y = 0.f; }

  float m = -INFINITY, lsum = 0.f;
  float scb = SCALE * cb[lane & 15];
  const float* hbase = hidden + ((size_t)b*S + s0)*E;

  int rA = lane & 15, gA = lane >> 4, rxA = rA & 7;
  int fbA0 = 72*w + 2*gA;
  int lb4 = lane >> 2, le = 2*(lane & 3);
  int fbP0 = 2*lb4 + (le >> 2), lo2 = le & 3;

  {
    const float* src = hbase;
    #pragma unroll
    for (int i=0;i<18;++i)
      GLOAD_LDS16(src + soff[i], smemf + (w*18 + i)*256);
  }

  for (int st=0; st<16; ++st){
    __syncthreads();
    float* tp = smemf + (st & 1)*18432;
    if (st+1 < 16){
      const float* src = hbase + (size_t)(st+1)*18432;
      float* dst = smemf + ((st+1) & 1)*18432;
      #pragma unroll
      for (int i=0;i<18;++i)
        GLOAD_LDS16(src + soff[i], dst + (w*18 + i)*256);
    }

    f32x4 d1 = {0.f,0.f,0.f,0.f};
    #pragma unroll
    for (int kk=0;kk<9;++kk){
      int fb0 = fbA0 + 8*kk;
      const float4 fa = *(const float4*)(tp + rA*1152 + ((fb0     ^ rxA) << 2));
      const float4 fc = *(const float4*)(tp + rA*1152 + (((fb0+1) ^ rxA) << 2));
      uint4v u;
      u[0] = cvtpk_bf16(fa.x, fa.y);
      u[1] = cvtpk_bf16(fa.z, fa.w);
      u[2] = cvtpk_bf16(fc.x, fc.y);
      u[3] = cvtpk_bf16(fc.z, fc.w);
      d1 = __builtin_amdgcn_mfma_f32_16x16x32_bf16(
             __builtin_bit_cast(short8, u), qkf[kk], d1, 0, 0, 0);
    }
    #pragma unroll
    for (int q=0;q<4;++q)
      D1[(w*16 + gA*4 + q)*17 + rA] = d1[q];

    LGKM_BAR();

    if (w == 0){
      int hh = lane & 15, gg = lane >> 4;
      float v[4];
      #pragma unroll
      for (int q=0;q<4;++q){
        int R = gg*4 + q;
        float raw = D1[R*17+hh] + D1[(16+R)*17+hh]
                  + D1[(32+R)*17+hh] + D1[(48+R)*17+hh];
        v[q] = fmaf(raw, SCALE, scb) + mask_lds[st*16 + R];
      }
      float sm = fmaxf(fmaxf(v[0],v[1]), fmaxf(v[2],v[3]));
      sm = fmaxf(sm, __shfl_xor(sm,16));
      sm = fmaxf(sm, __shfl_xor(sm,32));
      float f = 1.0f;
      if (__any(sm > m + 8.0f)){
        float mn = fmaxf(m, sm);
        f = __expf(m - mn);
        m = mn; lsum *= f;
      }
      if (lane < 16) f_lds[lane] = f;
      #pragma unroll
      for (int q=0;q<4;++q){
        float wq = __expf(v[q] - m);
        lsum += wq;
        wgt_lds[(gg*4+q)*16 + hh] = wq;
      }
    }

    LGKM_BAR();

    {
      const float4 fv = *(const float4*)(f_lds + 4*w);
      if (fv.x!=1.f || fv.y!=1.f || fv.z!=1.f || fv.w!=1.f){
        #pragma unroll
        for (int k=0;k<9;++k){
          acc[0][k].x*=fv.x; acc[0][k].y*=fv.x;
          acc[1][k].x*=fv.y; acc[1][k].y*=fv.y;
          acc[2][k].x*=fv.z; acc[2][k].y*=fv.z;
          acc[3][k].x*=fv.w; acc[3][k].y*=fv.w;
        }
      }
      #pragma unroll
      for (int r2=0; r2<16; ++r2){
        const float4 wg = *(const float4*)(wgt_lds + r2*16 + 4*w);
        int rx2 = r2 & 7;
        int rowb = r2*1152;
        #pragma unroll
        for (int k=0;k<9;++k){
          const float2 hv = *(const float2*)(tp + rowb + (((fbP0 + 32*k) ^ rx2) << 2) + lo2);
          acc[0][k].x = fmaf(wg.x, hv.x, acc[0][k].x); acc[0][k].y = fmaf(wg.x, hv.y, acc[0][k].y);
          acc[1][k].x = fmaf(wg.y, hv.x, acc[1][k].x); acc[1][k].y = fmaf(wg.y, hv.y, acc[1][k].y);
          acc[2][k].x = fmaf(wg.z, hv.x, acc[2][k].x); acc[2][k].y = fmaf(wg.z, hv.y, acc[2][k].y);
          acc[3][k].x = fmaf(wg.w, hv.x, acc[3][k].x); acc[3][k].y = fmaf(wg.w, hv.y, acc[3][k].y);
        }
      }
    }
  }

  if (w == 0){
    float lt = lsum + __shfl_xor(lsum, 16);
    lt += __shfl_xor(lt, 32);
    if (lane < 16){
      size_t o = ((size_t)(b*NSL + sl)*16 + lane)*2;
      part_ml[o] = m; part_ml[o+1] = lt;
    }
  }
  #pragma unroll
  for (int j=0;j<4;++j){
    float2* dst = (float2*)(part + ((size_t)(b*NSL + sl)*H + 4*w + j)*E);
    #pragma unroll
    for (int k=0;k<9;++k) dst[lane + 64*k] = acc[j][k];
  }
}

// ctx[b][h][e] = sum_sl part[b][sl][h][e] * exp(m_sl - M) / L
__global__ void k_ctxred(const float* __restrict__ part, const float* __restrict__ part_ml,
                         float* __restrict__ ctx){
  int idx = blockIdx.x*256 + threadIdx.x;  // < B*H*E
  int b = idx / (H*E); int he = idx % (H*E); int h = he / E;
  float M = -INFINITY, L = 0.f;
  #pragma unroll 4
  for (int c = 0; c < NSL; ++c){
    size_t o = ((size_t)(b*NSL + c)*16 + h)*2;
    float om = part_ml[o], ol = part_ml[o+1];
    float nm = fmaxf(M, om);
    L = L*__expf(M - nm) + ol*__expf(om - nm);
    M = nm;
  }
  float invL = 1.0f / L;
  float s = 0.f;
  #pragma unroll 4
  for (int sl=0; sl<NSL; ++sl){
    float scl = __expf(part_ml[((size_t)(b*NSL + sl)*16 + h)*2] - M) * invL;
    s = fmaf(part[(size_t)(b*NSL+sl)*H*E + he], scl, s);
  }
  ctx[idx] = s;
}

// pooled[b, j] = wv[j,:]·ctx[b, j/72, :] + bv[j]   (float2 loads)
__global__ void k_pool(const float* __restrict__ ctx, const float* __restrict__ ipw,
                       const float* __restrict__ ipb, float* __restrict__ pooled){
  int tid = threadIdx.x, lane = tid & 63, w = tid >> 6;
  int j = blockIdx.x*4 + w;
  int h = j / HD;
  const float2* wr = (const float2*)(ipw + (size_t)2*E*E + (size_t)j*E);
  float acc[32];
  #pragma unroll
  for (int b_=0;b_<32;++b_) acc[b_]=0.f;
  #pragma unroll
  for (int t=0;t<9;++t){
    int e2 = lane + 64*t;
    float2 wv = wr[e2];
    #pragma unroll
    for (int b_=0;b_<32;++b_){
      float2 cv = *(const float2*)(ctx + (size_t)(b_*H + h)*E + 2*e2);
      acc[b_] = fmaf(wv.x, cv.x, fmaf(wv.y, cv.y, acc[b_]));
    }
  }
  #pragma unroll
  for (int b_=0;b_<32;++b_){
    float s = wredsum(acc[b_]);
    if (lane==b_) pooled[(size_t)b_*E + j] = s + ipb[2*E + j];
  }
}

// resid[b,i] = out_w[i,:]·pooled[b,:] + out_b[i]   (float2 loads)
__global__ void k_outproj(const float* __restrict__ pooled, const float* __restrict__ ow,
                          const float* __restrict__ ob, float* __restrict__ resid){
  int tid = threadIdx.x, lane = tid & 63, w = tid >> 6;
  int i = blockIdx.x*4 + w;
  const float2* wr = (const float2*)(ow + (size_t)i*E);
  float acc[32];
  #pragma unroll
  for (int b_=0;b_<32;++b_) acc[b_]=0.f;
  #pragma unroll
  for (int t=0;t<9;++t){
    int e2 = lane + 64*t;
    float2 wv = wr[e2];
    #pragma unroll
    for (int b_=0;b_<32;++b_){
      float2 pv = *(const float2*)(pooled + (size_t)b_*E + 2*e2);
      acc[b_] = fmaf(wv.x, pv.x, fmaf(wv.y, pv.y, acc[b_]));
    }
  }
  #pragma unroll
  for (int b_=0;b_<32;++b_){
    float s = wredsum(acc[b_]);
    if (lane==b_) resid[(size_t)b_*E + i] = s + ob[i];
  }
}

__global__ void k_ln(const float* __restrict__ resid, const float* __restrict__ g,
                     const float* __restrict__ be, float* __restrict__ x){
  __shared__ float red[8];
  int b = blockIdx.x, tid = threadIdx.x, lane = tid & 63, w = tid >> 6;
  const float* r = resid + (size_t)b*E;
  float s = 0.f, s2 = 0.f;
  for (int e=tid; e<E; e+=256){ float v = r[e]; s += v; s2 = fmaf(v,v,s2); }
  s = wredsum(s); s2 = wredsum(s2);
  if (lane==0){ red[w]=s; red[4+w]=s2; }
  __syncthreads();
  float S1 = red[0]+red[1]+red[2]+red[3];
  float S2 = red[4]+red[5]+red[6]+red[7];
  float mu  = S1*(1.0f/E);
  float var = S2*(1.0f/E) - mu*mu;
  float inv = rsqrtf(var + 1e-6f);
  for (int e=tid; e<E; e+=256){
    float v = (r[e]-mu)*inv;
    x[(size_t)b*E + e] = v*g[e] + be[e];
  }
}

__device__ __forceinline__ float gelu_tanh(float u){
  float u3 = u*u*u;
  float t = tanhf(0.7978845608028654f*(u + 0.044715f*u3));
  return 0.5f*u*(1.0f+t);
}

// h1[b,i] = gelu(x·fc1_w[i,:]+b1[i]); float2 loads, wave = 2 outputs
__global__ __launch_bounds__(256) void k_fc1(
    const float* __restrict__ x, const float* __restrict__ w1,
    const float* __restrict__ b1, float* __restrict__ h1){
  int tid = threadIdx.x, lane = tid & 63, w = tid >> 6;
  int wid = blockIdx.x*4 + w;      // < 2152
  int i0 = wid*2;
  float acc[2][32];
  #pragma unroll
  for (int ii=0;ii<2;++ii)
    #pragma unroll
    for (int b_=0;b_<32;++b_) acc[ii][b_]=0.f;
  const float2* w1a = (const float2*)(w1 + (size_t)i0*E);
  const float2* w1b = (const float2*)(w1 + (size_t)(i0+1)*E);
  #pragma unroll
  for (int t=0;t<9;++t){
    int e2 = lane + 64*t;
    float2 f0 = w1a[e2];
    float2 f1 = w1b[e2];
    #pragma unroll
    for (int b_=0;b_<32;++b_){
      float2 xv = *(const float2*)(x + (size_t)b_*E + 2*e2);
      acc[0][b_] = fmaf(f0.x, xv.x, fmaf(f0.y, xv.y, acc[0][b_]));
      acc[1][b_] = fmaf(f1.x, xv.x, fmaf(f1.y, xv.y, acc[1][b_]));
    }
  }
  #pragma unroll
  for (int ii=0;ii<2;++ii)
    #pragma unroll
    for (int b_=0;b_<32;++b_){
      float s = wredsum(acc[ii][b_]);
      if (lane==b_) h1[(size_t)b_*IDIM + i0 + ii] = gelu_tanh(s + b1[i0+ii]);
    }
}

// out[b,i] = resid + h1·fc2_w[i,:] + b2[i]; block = 2 outputs, 4-way K-split
__global__ __launch_bounds__(256) void k_fc2(
    const float* __restrict__ h1, const float* __restrict__ w2,
    const float* __restrict__ b2, const float* __restrict__ resid,
    float* __restrict__ out){
  __shared__ float red[4][2][32];
  int tid = threadIdx.x, lane = tid & 63, w = tid >> 6;
  int i0 = blockIdx.x*2;           // 576 blocks
  float acc[2][32];
  #pragma unroll
  for (int ii=0;ii<2;++ii)
    #pragma unroll
    for (int b_=0;b_<32;++b_) acc[ii][b_]=0.f;
  // wave w covers t = w, w+4, ... (17 iters each)
  for (int t=w; t<68; t+=4){
    int e = lane + 64*t;
    if (e < IDIM){
      float f0 = w2[(size_t)i0*IDIM + e];
      float f1 = w2[(size_t)(i0+1)*IDIM + e];
      #pragma unroll
      for (int b_=0;b_<32;++b_){
        float hvv = h1[(size_t)b_*IDIM + e];
        acc[0][b_] = fmaf(f0, hvv, acc[0][b_]);
        acc[1][b_] = fmaf(f1, hvv, acc[1][b_]);
      }
    }
  }
  #pragma unroll
  for (int ii=0;ii<2;++ii)
    #pragma unroll
    for (int b_=0;b_<32;++b_){
      float s = wredsum(acc[ii][b_]);
      if (lane==b_) red[w][ii][b_] = s;
    }
  __syncthreads();
  if (tid < 64){
    int b_ = tid & 31, ii = tid >> 5;
    float s = red[0][ii][b_] + red[1][ii][b_] + red[2][ii][b_] + red[3][ii][b_];
    int i = i0 + ii;
    out[(size_t)b_*E + i] = resid[(size_t)b_*E + i] + s + b2[i];
  }
}

extern "C" void kernel_launch(void* const* d_in, const int* in_sizes, int n_in,
                              void* d_out, int out_size, void* d_ws, size_t ws_size,
                              hipStream_t stream){
  const float* hidden = (const float*)d_in[0];
  const int*   mask   = (const int*)d_in[1];
  const float* probe  = (const float*)d_in[2];
  const float* ipw    = (const float*)d_in[3];
  const float* ipb    = (const float*)d_in[4];
  const float* ow     = (const float*)d_in[5];
  const float* ob     = (const float*)d_in[6];
  const float* ln_g   = (const float*)d_in[7];
  const float* ln_b   = (const float*)d_in[8];
  const float* w1     = (const float*)d_in[9];
  const float* b1     = (const float*)d_in[10];
  const float* w2     = (const float*)d_in[11];
  const float* b2     = (const float*)d_in[12];
  float* out = (float*)d_out;
  float* ws  = (float*)d_ws;

  size_t off = 0;
  float* q  = ws + off; off += E;
  float* cb = ws + off; off += 16;
  unsigned short* qkfrag = (unsigned short*)(ws + off); off += 9216;
  float* part_ml = ws + off; off += 32*NSL*16*2;
  float* part    = ws + off; off += (size_t)B*NSL*H*E;  // 37.7 MB
  float* ctx     = ws + off; off += (size_t)B*H*E;
  float* pooled  = ws + off; off += (size_t)B*E;
  float* resid   = ws + off; off += (size_t)B*E;
  float* x       = ws + off; off += (size_t)B*E;
  float* h1      = ws + off;

  k_q       <<<288, 256, 0, stream>>>(probe, ipw, ipb, q);
  k_qk      <<<72, 256, 0, stream>>>(q, ipw, ipb, qkfrag, cb);
  k_fused   <<<B*NSL, 256, 0, stream>>>(hidden, qkfrag, cb, mask, part, part_ml);
  k_ctxred  <<<2304, 256, 0, stream>>>(part, part_ml, ctx);
  k_pool    <<<288, 256, 0, stream>>>(ctx, ipw, ipb, pooled);
  k_outproj <<<288, 256, 0, stream>>>(pooled, ow, ob, resid);
  k_ln      <<<32, 256, 0, stream>>>(resid, ln_g, ln_b, x);
  k_fc1     <<<538, 256, 0, stream>>>(x, w1, b1, h1);
  k_fc2     <<<576, 256, 0, stream>>>(h1, w2, b2, resid, out);
}

// Round 9
// 368.045 us; speedup vs baseline: 3.2958x; 2.2743x over previous
//
#include <hip/hip_runtime.h>
#include <math.h>

#define E 1152
#define H 16
#define HD 72
#define B 32
#define S 4096
#define IDIM 4304
#define NSL 16

#define NEGF (-3.402823466e38f)
#define SCALE 0.1178511301977579f  // 1/sqrt(72)

typedef short short8 __attribute__((ext_vector_type(8)));
typedef float f32x4 __attribute__((ext_vector_type(4)));
typedef unsigned int uint4v __attribute__((ext_vector_type(4)));

#define GLOAD_LDS16(gp, lp) __builtin_amdgcn_global_load_lds( \
    (const __attribute__((address_space(1))) unsigned int*)(gp), \
    (__attribute__((address_space(3))) unsigned int*)(lp), 16, 0, 0)

#define LGKM_BAR() do { asm volatile("s_waitcnt lgkmcnt(0)" ::: "memory"); \
                        __builtin_amdgcn_s_barrier(); } while(0)

__device__ __forceinline__ unsigned int cvtpk_bf16(float lo, float hi){
  unsigned int r;
  asm("v_cvt_pk_bf16_f32 %0, %1, %2" : "=v"(r) : "v"(lo), "v"(hi));
  return r;
}

__device__ __forceinline__ unsigned short f2bf(float x){
  unsigned int u = __float_as_uint(x);
  u = (u + 0x7fffu + ((u >> 16) & 1u)) >> 16;   // RNE
  return (unsigned short)u;
}

__device__ __forceinline__ float wredsum(float v){
  v += __shfl_xor(v,32); v += __shfl_xor(v,16); v += __shfl_xor(v,8);
  v += __shfl_xor(v,4);  v += __shfl_xor(v,2);  v += __shfl_xor(v,1);
  return v;
}

// q[j] = probe . wq[j,:] + bq[j]   (float2 loads)
__global__ void k_q(const float* __restrict__ probe, const float* __restrict__ ipw,
                    const float* __restrict__ ipb, float* __restrict__ q){
  int tid = threadIdx.x, lane = tid & 63, w = tid >> 6;
  int j = blockIdx.x*4 + w;
  const float2* wr = (const float2*)(ipw + (size_t)j*E);
  const float2* pr = (const float2*)probe;
  float s = 0.f;
  #pragma unroll
  for (int t=0;t<9;++t){
    int e2 = lane + 64*t;
    float2 a = pr[e2], b = wr[e2];
    s = fmaf(a.x, b.x, fmaf(a.y, b.y, s));
  }
  s = wredsum(s);
  if (lane==0) q[j] = s + ipb[j];
}

// qk[h][e] -> bf16 B-frag order: kk = e>>5, lane = ((e>>3)&3)*16 + h, j = e&7
__global__ void k_qk(const float* __restrict__ q, const float* __restrict__ ipw,
                     const float* __restrict__ ipb, unsigned short* __restrict__ qkfrag,
                     float* __restrict__ cb){
  int idx = blockIdx.x*256 + threadIdx.x;   // < H*E
  int h = idx / E, e = idx % E;
  float s = 0.f;
  #pragma unroll 8
  for (int d=0; d<HD; ++d)
    s = fmaf(q[h*HD+d], ipw[(size_t)(E + h*HD + d)*E + e], s);
  int kk = e >> 5, g = (e >> 3) & 3, j = e & 7;
  qkfrag[(size_t)kk*512 + (g*16 + h)*8 + j] = f2bf(s);
  if (idx < H){
    float c = 0.f;
    for (int d=0; d<HD; ++d) c = fmaf(q[idx*HD+d], ipb[E + idx*HD + d], c);
    cb[idx] = c;
  }
}

// ---------------- fused flash pass (unchanged from R7/R8)
__global__ __launch_bounds__(256) void k_fused(
    const float* __restrict__ hidden, const unsigned short* __restrict__ qkfrag,
    const float* __restrict__ cb, const int* __restrict__ mask,
    float* __restrict__ part, float* __restrict__ part_ml){
  __shared__ float smemf[38480];
  float* D1       = smemf + 36864;
  float* f_lds    = smemf + 37952;
  float* wgt_lds  = smemf + 37968;
  float* mask_lds = smemf + 38224;

  int tid = threadIdx.x, lane = tid & 63, w = tid >> 6;
  int b = blockIdx.x >> 4, sl = blockIdx.x & 15;
  int s0 = sl * 256;

  mask_lds[tid] = (1.0f - (float)mask[(size_t)b*S + s0 + tid]) * NEGF;

  short8 qkf[9];
  {
    const short8* qf = (const short8*)qkfrag;
    #pragma unroll
    for (int kk=0;kk<9;++kk) qkf[kk] = qf[(9*w + kk)*64 + lane];
  }

  int soff[18];
  #pragma unroll
  for (int i=0;i<18;++i){
    int d = (w*18 + i)*256 + lane*4;
    int r = d / 1152;
    int o = d - r*1152;
    int fb = o >> 2;
    soff[i] = r*1152 + ((fb ^ (r & 7)) << 2);
  }

  float2 acc[4][9];
  #pragma unroll
  for (int j=0;j<4;++j)
    #pragma unroll
    for (int k=0;k<9;++k){ acc[j][k].x = 0.f; acc[j][k].y = 0.f; }

  float m = -INFINITY, lsum = 0.f;
  float scb = SCALE * cb[lane & 15];
  const float* hbase = hidden + ((size_t)b*S + s0)*E;

  int rA = lane & 15, gA = lane >> 4, rxA = rA & 7;
  int fbA0 = 72*w + 2*gA;
  int lb4 = lane >> 2, le = 2*(lane & 3);
  int fbP0 = 2*lb4 + (le >> 2), lo2 = le & 3;

  {
    const float* src = hbase;
    #pragma unroll
    for (int i=0;i<18;++i)
      GLOAD_LDS16(src + soff[i], smemf + (w*18 + i)*256);
  }

  for (int st=0; st<16; ++st){
    __syncthreads();
    float* tp = smemf + (st & 1)*18432;
    if (st+1 < 16){
      const float* src = hbase + (size_t)(st+1)*18432;
      float* dst = smemf + ((st+1) & 1)*18432;
      #pragma unroll
      for (int i=0;i<18;++i)
        GLOAD_LDS16(src + soff[i], dst + (w*18 + i)*256);
    }

    f32x4 d1 = {0.f,0.f,0.f,0.f};
    #pragma unroll
    for (int kk=0;kk<9;++kk){
      int fb0 = fbA0 + 8*kk;
      const float4 fa = *(const float4*)(tp + rA*1152 + ((fb0     ^ rxA) << 2));
      const float4 fc = *(const float4*)(tp + rA*1152 + (((fb0+1) ^ rxA) << 2));
      uint4v u;
      u[0] = cvtpk_bf16(fa.x, fa.y);
      u[1] = cvtpk_bf16(fa.z, fa.w);
      u[2] = cvtpk_bf16(fc.x, fc.y);
      u[3] = cvtpk_bf16(fc.z, fc.w);
      d1 = __builtin_amdgcn_mfma_f32_16x16x32_bf16(
             __builtin_bit_cast(short8, u), qkf[kk], d1, 0, 0, 0);
    }
    #pragma unroll
    for (int q=0;q<4;++q)
      D1[(w*16 + gA*4 + q)*17 + rA] = d1[q];

    LGKM_BAR();

    if (w == 0){
      int hh = lane & 15, gg = lane >> 4;
      float v[4];
      #pragma unroll
      for (int q=0;q<4;++q){
        int R = gg*4 + q;
        float raw = D1[R*17+hh] + D1[(16+R)*17+hh]
                  + D1[(32+R)*17+hh] + D1[(48+R)*17+hh];
        v[q] = fmaf(raw, SCALE, scb) + mask_lds[st*16 + R];
      }
      float sm = fmaxf(fmaxf(v[0],v[1]), fmaxf(v[2],v[3]));
      sm = fmaxf(sm, __shfl_xor(sm,16));
      sm = fmaxf(sm, __shfl_xor(sm,32));
      float f = 1.0f;
      if (__any(sm > m + 8.0f)){
        float mn = fmaxf(m, sm);
        f = __expf(m - mn);
        m = mn; lsum *= f;
      }
      if (lane < 16) f_lds[lane] = f;
      #pragma unroll
      for (int q=0;q<4;++q){
        float wq = __expf(v[q] - m);
        lsum += wq;
        wgt_lds[(gg*4+q)*16 + hh] = wq;
      }
    }

    LGKM_BAR();

    {
      const float4 fv = *(const float4*)(f_lds + 4*w);
      if (fv.x!=1.f || fv.y!=1.f || fv.z!=1.f || fv.w!=1.f){
        #pragma unroll
        for (int k=0;k<9;++k){
          acc[0][k].x*=fv.x; acc[0][k].y*=fv.x;
          acc[1][k].x*=fv.y; acc[1][k].y*=fv.y;
          acc[2][k].x*=fv.z; acc[2][k].y*=fv.z;
          acc[3][k].x*=fv.w; acc[3][k].y*=fv.w;
        }
      }
      #pragma unroll
      for (int r2=0; r2<16; ++r2){
        const float4 wg = *(const float4*)(wgt_lds + r2*16 + 4*w);
        int rx2 = r2 & 7;
        int rowb = r2*1152;
        #pragma unroll
        for (int k=0;k<9;++k){
          const float2 hv = *(const float2*)(tp + rowb + (((fbP0 + 32*k) ^ rx2) << 2) + lo2);
          acc[0][k].x = fmaf(wg.x, hv.x, acc[0][k].x); acc[0][k].y = fmaf(wg.x, hv.y, acc[0][k].y);
          acc[1][k].x = fmaf(wg.y, hv.x, acc[1][k].x); acc[1][k].y = fmaf(wg.y, hv.y, acc[1][k].y);
          acc[2][k].x = fmaf(wg.z, hv.x, acc[2][k].x); acc[2][k].y = fmaf(wg.z, hv.y, acc[2][k].y);
          acc[3][k].x = fmaf(wg.w, hv.x, acc[3][k].x); acc[3][k].y = fmaf(wg.w, hv.y, acc[3][k].y);
        }
      }
    }
  }

  if (w == 0){
    float lt = lsum + __shfl_xor(lsum, 16);
    lt += __shfl_xor(lt, 32);
    if (lane < 16){
      size_t o = ((size_t)(b*NSL + sl)*16 + lane)*2;
      part_ml[o] = m; part_ml[o+1] = lt;
    }
  }
  #pragma unroll
  for (int j=0;j<4;++j){
    float2* dst = (float2*)(part + ((size_t)(b*NSL + sl)*H + 4*w + j)*E);
    #pragma unroll
    for (int k=0;k<9;++k) dst[lane + 64*k] = acc[j][k];
  }
}

// ctx[b][h][e] = sum_sl part[b][sl][h][e] * exp(m_sl - M) / L
__global__ void k_ctxred(const float* __restrict__ part, const float* __restrict__ part_ml,
                         float* __restrict__ ctx){
  int idx = blockIdx.x*256 + threadIdx.x;  // < B*H*E
  int b = idx / (H*E); int he = idx % (H*E); int h = he / E;
  float M = -INFINITY, L = 0.f;
  #pragma unroll 4
  for (int c = 0; c < NSL; ++c){
    size_t o = ((size_t)(b*NSL + c)*16 + h)*2;
    float om = part_ml[o], ol = part_ml[o+1];
    float nm = fmaxf(M, om);
    L = L*__expf(M - nm) + ol*__expf(om - nm);
    M = nm;
  }
  float invL = 1.0f / L;
  float s = 0.f;
  #pragma unroll 4
  for (int sl=0; sl<NSL; ++sl){
    float scl = __expf(part_ml[((size_t)(b*NSL + sl)*16 + h)*2] - M) * invL;
    s = fmaf(part[(size_t)(b*NSL+sl)*H*E + he], scl, s);
  }
  ctx[idx] = s;
}

// pooled[b, j] = wv[j,:]·ctx[b, j/72, :] + bv[j]
// block = 1 j, 4 waves K-split over 9 float2-iters, LDS combine
__global__ __launch_bounds__(256) void k_pool(
    const float* __restrict__ ctx, const float* __restrict__ ipw,
    const float* __restrict__ ipb, float* __restrict__ pooled){
  __shared__ float red[4][32];
  int tid = threadIdx.x, lane = tid & 63, w = tid >> 6;
  int j = blockIdx.x;
  int h = j / HD;
  const float2* wr = (const float2*)(ipw + (size_t)2*E*E + (size_t)j*E);
  float acc[32];
  #pragma unroll
  for (int b_=0;b_<32;++b_) acc[b_]=0.f;
  for (int t=w; t<9; t+=4){
    int e2 = lane + 64*t;
    float2 wv = wr[e2];
    #pragma unroll
    for (int b_=0;b_<32;++b_){
      float2 cv = *(const float2*)(ctx + (size_t)(b_*H + h)*E + 2*e2);
      acc[b_] = fmaf(wv.x, cv.x, fmaf(wv.y, cv.y, acc[b_]));
    }
  }
  #pragma unroll
  for (int b_=0;b_<32;++b_){
    float s = wredsum(acc[b_]);
    if (lane==b_) red[w][b_] = s;
  }
  __syncthreads();
  if (tid < 32){
    float s = red[0][tid] + red[1][tid] + red[2][tid] + red[3][tid];
    pooled[(size_t)tid*E + j] = s + ipb[2*E + j];
  }
}

// resid[b,i] = out_w[i,:]·pooled[b,:] + out_b[i]  (same K-split structure)
__global__ __launch_bounds__(256) void k_outproj(
    const float* __restrict__ pooled, const float* __restrict__ ow,
    const float* __restrict__ ob, float* __restrict__ resid){
  __shared__ float red[4][32];
  int tid = threadIdx.x, lane = tid & 63, w = tid >> 6;
  int i = blockIdx.x;
  const float2* wr = (const float2*)(ow + (size_t)i*E);
  float acc[32];
  #pragma unroll
  for (int b_=0;b_<32;++b_) acc[b_]=0.f;
  for (int t=w; t<9; t+=4){
    int e2 = lane + 64*t;
    float2 wv = wr[e2];
    #pragma unroll
    for (int b_=0;b_<32;++b_){
      float2 pv = *(const float2*)(pooled + (size_t)b_*E + 2*e2);
      acc[b_] = fmaf(wv.x, pv.x, fmaf(wv.y, pv.y, acc[b_]));
    }
  }
  #pragma unroll
  for (int b_=0;b_<32;++b_){
    float s = wredsum(acc[b_]);
    if (lane==b_) red[w][b_] = s;
  }
  __syncthreads();
  if (tid < 32){
    float s = red[0][tid] + red[1][tid] + red[2][tid] + red[3][tid];
    resid[(size_t)tid*E + i] = s + ob[i];
  }
}

__global__ void k_ln(const float* __restrict__ resid, const float* __restrict__ g,
                     const float* __restrict__ be, float* __restrict__ x){
  __shared__ float red[8];
  int b = blockIdx.x, tid = threadIdx.x, lane = tid & 63, w = tid >> 6;
  const float* r = resid + (size_t)b*E;
  float s = 0.f, s2 = 0.f;
  for (int e=tid; e<E; e+=256){ float v = r[e]; s += v; s2 = fmaf(v,v,s2); }
  s = wredsum(s); s2 = wredsum(s2);
  if (lane==0){ red[w]=s; red[4+w]=s2; }
  __syncthreads();
  float S1 = red[0]+red[1]+red[2]+red[3];
  float S2 = red[4]+red[5]+red[6]+red[7];
  float mu  = S1*(1.0f/E);
  float var = S2*(1.0f/E) - mu*mu;
  float inv = rsqrtf(var + 1e-6f);
  for (int e=tid; e<E; e+=256){
    float v = (r[e]-mu)*inv;
    x[(size_t)b*E + e] = v*g[e] + be[e];
  }
}

__device__ __forceinline__ float gelu_tanh(float u){
  float u3 = u*u*u;
  float t = tanhf(0.7978845608028654f*(u + 0.044715f*u3));
  return 0.5f*u*(1.0f+t);
}

// h1[b,i] = gelu(x·fc1_w[i,:]+b1[i]); block = 2 outputs, 4-way K-split
__global__ __launch_bounds__(256) void k_fc1(
    const float* __restrict__ x, const float* __restrict__ w1,
    const float* __restrict__ b1, float* __restrict__ h1){
  __shared__ float red[4][2][32];
  int tid = threadIdx.x, lane = tid & 63, w = tid >> 6;
  int i0 = blockIdx.x*2;           // 2152 blocks
  float acc[2][32];
  #pragma unroll
  for (int ii=0;ii<2;++ii)
    #pragma unroll
    for (int b_=0;b_<32;++b_) acc[ii][b_]=0.f;
  const float2* w1a = (const float2*)(w1 + (size_t)i0*E);
  const float2* w1b = (const float2*)(w1 + (size_t)(i0+1)*E);
  for (int t=w; t<9; t+=4){
    int e2 = lane + 64*t;
    float2 f0 = w1a[e2];
    float2 f1 = w1b[e2];
    #pragma unroll
    for (int b_=0;b_<32;++b_){
      float2 xv = *(const float2*)(x + (size_t)b_*E + 2*e2);
      acc[0][b_] = fmaf(f0.x, xv.x, fmaf(f0.y, xv.y, acc[0][b_]));
      acc[1][b_] = fmaf(f1.x, xv.x, fmaf(f1.y, xv.y, acc[1][b_]));
    }
  }
  #pragma unroll
  for (int ii=0;ii<2;++ii)
    #pragma unroll
    for (int b_=0;b_<32;++b_){
      float s = wredsum(acc[ii][b_]);
      if (lane==b_) red[w][ii][b_] = s;
    }
  __syncthreads();
  if (tid < 64){
    int b_ = tid & 31, ii = tid >> 5;
    float s = red[0][ii][b_] + red[1][ii][b_] + red[2][ii][b_] + red[3][ii][b_];
    h1[(size_t)b_*IDIM + i0 + ii] = gelu_tanh(s + b1[i0+ii]);
  }
}

// out[b,i] = resid + h1·fc2_w[i,:] + b2[i]; block = 2 outputs, 4-way K-split
__global__ __launch_bounds__(256) void k_fc2(
    const float* __restrict__ h1, const float* __restrict__ w2,
    const float* __restrict__ b2, const float* __restrict__ resid,
    float* __restrict__ out){
  __shared__ float red[4][2][32];
  int tid = threadIdx.x, lane = tid & 63, w = tid >> 6;
  int i0 = blockIdx.x*2;           // 576 blocks
  float acc[2][32];
  #pragma unroll
  for (int ii=0;ii<2;++ii)
    #pragma unroll
    for (int b_=0;b_<32;++b_) acc[ii][b_]=0.f;
  for (int t=w; t<68; t+=4){
    int e = lane + 64*t;
    if (e < IDIM){
      float f0 = w2[(size_t)i0*IDIM + e];
      float f1 = w2[(size_t)(i0+1)*IDIM + e];
      #pragma unroll
      for (int b_=0;b_<32;++b_){
        float hvv = h1[(size_t)b_*IDIM + e];
        acc[0][b_] = fmaf(f0, hvv, acc[0][b_]);
        acc[1][b_] = fmaf(f1, hvv, acc[1][b_]);
      }
    }
  }
  #pragma unroll
  for (int ii=0;ii<2;++ii)
    #pragma unroll
    for (int b_=0;b_<32;++b_){
      float s = wredsum(acc[ii][b_]);
      if (lane==b_) red[w][ii][b_] = s;
    }
  __syncthreads();
  if (tid < 64){
    int b_ = tid & 31, ii = tid >> 5;
    float s = red[0][ii][b_] + red[1][ii][b_] + red[2][ii][b_] + red[3][ii][b_];
    int i = i0 + ii;
    out[(size_t)b_*E + i] = resid[(size_t)b_*E + i] + s + b2[i];
  }
}

extern "C" void kernel_launch(void* const* d_in, const int* in_sizes, int n_in,
                              void* d_out, int out_size, void* d_ws, size_t ws_size,
                              hipStream_t stream){
  const float* hidden = (const float*)d_in[0];
  const int*   mask   = (const int*)d_in[1];
  const float* probe  = (const float*)d_in[2];
  const float* ipw    = (const float*)d_in[3];
  const float* ipb    = (const float*)d_in[4];
  const float* ow     = (const float*)d_in[5];
  const float* ob     = (const float*)d_in[6];
  const float* ln_g   = (const float*)d_in[7];
  const float* ln_b   = (const float*)d_in[8];
  const float* w1     = (const float*)d_in[9];
  const float* b1     = (const float*)d_in[10];
  const float* w2     = (const float*)d_in[11];
  const float* b2     = (const float*)d_in[12];
  float* out = (float*)d_out;
  float* ws  = (float*)d_ws;

  size_t off = 0;
  float* q  = ws + off; off += E;
  float* cb = ws + off; off += 16;
  unsigned short* qkfrag = (unsigned short*)(ws + off); off += 9216;
  float* part_ml = ws + off; off += 32*NSL*16*2;
  float* part    = ws + off; off += (size_t)B*NSL*H*E;  // 37.7 MB
  float* ctx     = ws + off; off += (size_t)B*H*E;
  float* pooled  = ws + off; off += (size_t)B*E;
  float* resid   = ws + off; off += (size_t)B*E;
  float* x       = ws + off; off += (size_t)B*E;
  float* h1      = ws + off;

  k_q       <<<288, 256, 0, stream>>>(probe, ipw, ipb, q);
  k_qk      <<<72, 256, 0, stream>>>(q, ipw, ipb, qkfrag, cb);
  k_fused   <<<B*NSL, 256, 0, stream>>>(hidden, qkfrag, cb, mask, part, part_ml);
  k_ctxred  <<<2304, 256, 0, stream>>>(part, part_ml, ctx);
  k_pool    <<<1152, 256, 0, stream>>>(ctx, ipw, ipb, pooled);
  k_outproj <<<1152, 256, 0, stream>>>(pooled, ow, ob, resid);
  k_ln      <<<32, 256, 0, stream>>>(resid, ln_g, ln_b, x);
  k_fc1     <<<2152, 256, 0, stream>>>(x, w1, b1, h1);
  k_fc2     <<<576, 256, 0, stream>>>(h1, w2, b2, resid, out);
}